// Round 5
// baseline (1228.576 us; speedup 1.0000x reference)
//
#include <hip/hip_runtime.h>
#include <hip/hip_bf16.h>
#include <math.h>

#define B_      32
#define H_      56
#define W_      56
#define C_      384
#define HEADS_  12
#define WIN_    7
#define SHIFT_  3
#define NTOK_   49
#define HD_     32
#define T_      100352   // B_*H_*W_
#define MLP_    1536

typedef __bf16 bf16x8 __attribute__((ext_vector_type(8)));
typedef unsigned short u16x8 __attribute__((ext_vector_type(8)));
typedef float  f32x4  __attribute__((ext_vector_type(4)));

__device__ __forceinline__ float bf2f(unsigned short u) {
  union { unsigned int i; float f; } v; v.i = ((unsigned int)u) << 16; return v.f;
}
__device__ __forceinline__ unsigned short f2bf(float f) {
  union { float f; unsigned int i; } v; v.f = f;
  unsigned int x = v.i;
  return (unsigned short)((x + 0x7fffu + ((x >> 16) & 1u)) >> 16);
}
// fast tanh-GELU (max |err| vs exact ~1e-3; safe for bf16-level tolerance)
__device__ __forceinline__ float gelu_fast(float x) {
  const float t = 0.79788456f * x * (1.0f + 0.044715f * x * x);
  const float e = __expf(2.0f * t);
  const float th = 1.0f - 2.0f / (e + 1.0f);   // tanh(t), inf-safe
  return 0.5f * x * (1.0f + th);
}
__device__ __forceinline__ void gload_lds16(const void* g, void* l) {
  __builtin_amdgcn_global_load_lds(
      (const __attribute__((address_space(1))) void*)g,
      (__attribute__((address_space(3))) void*)l, 16, 0, 0);
}
__device__ __forceinline__ bf16x8 ldg8(const unsigned short* p) {
  u16x8 v = *(const u16x8*)p;
  return __builtin_bit_cast(bf16x8, v);
}

// ---------------- f32 -> bf16 weight convert (n divisible by 1024) ----------
__global__ __launch_bounds__(256)
void wconv_kernel(const float* __restrict__ src, unsigned short* __restrict__ dst, int n) {
  const int i = (blockIdx.x * 256 + threadIdx.x) * 4;
  if (i < n) {
    const float4 v = *(const float4*)(src + i);
    ushort4 o;
    o.x = f2bf(v.x); o.y = f2bf(v.y); o.z = f2bf(v.z); o.w = f2bf(v.w);
    *(ushort4*)(dst + i) = o;
  }
}

// ---------------- LayerNorm: 4 rows / 256-thread block ----------------------
template<int REMAP>
__global__ __launch_bounds__(256)
void ln_kernel(const float* __restrict__ xin, const float* __restrict__ g,
               const float* __restrict__ bb, unsigned short* __restrict__ outbf) {
  const int m = blockIdx.x * 4 + (threadIdx.x >> 6);
  const int lane = threadIdx.x & 63;
  size_t src;
  if (REMAP) {
    int w = m / NTOK_, t = m - w * NTOK_;
    int bz = w >> 6, widx = w & 63;
    int wh = widx >> 3, ww = widx & 7;
    int ih = t / WIN_, iw = t - ih * WIN_;
    int gh = (wh * WIN_ + ih + SHIFT_) % H_;
    int gw = (ww * WIN_ + iw + SHIFT_) % W_;
    src = ((size_t)bz * (H_ * W_) + gh * W_ + gw) * C_;
  } else {
    src = (size_t)m * C_;
  }
  const float* row = xin + src;
  float v[6]; float s = 0.f, s2 = 0.f;
#pragma unroll
  for (int u = 0; u < 6; ++u) {
    v[u] = row[lane + 64 * u];
    s += v[u]; s2 += v[u] * v[u];
  }
#pragma unroll
  for (int off = 32; off; off >>= 1) {
    s  += __shfl_xor(s, off);
    s2 += __shfl_xor(s2, off);
  }
  const float mean = s * (1.0f / C_);
  const float var  = s2 * (1.0f / C_) - mean * mean;
  const float rstd = rsqrtf(var + 1e-5f);
  unsigned short* orow = outbf + (size_t)m * C_;
#pragma unroll
  for (int u = 0; u < 6; ++u) {
    int c = lane + 64 * u;
    orow[c] = f2bf((v[u] - mean) * rstd * g[c] + bb[c]);
  }
}

// ---------------- MFMA GEMM (bf16 weights via global_load_lds) --------------
// EPI: 0 bf16 store; 2 window-reverse+unshift+resid -> f32 d_out
#define BM 128
#define BN 128
#define BKg 64

template<int EPI>
__global__ __launch_bounds__(256)
void mfma_gemm(const unsigned short* __restrict__ A,   // [M,K] bf16
               const unsigned short* __restrict__ Wb,  // [N,K] bf16
               const float* __restrict__ bias,
               void* __restrict__ outv,
               const float* __restrict__ resid,
               int M, int Nn, int K) {
  __shared__ unsigned short Al[BM * BKg];
  __shared__ unsigned short Bl[BN * BKg];
  const int t    = threadIdx.x;
  const int wid  = t >> 6;
  const int lane = t & 63;
  const int wr   = wid >> 1, wc = wid & 1;

  const unsigned int nb = gridDim.x * gridDim.y;
  unsigned int lin = blockIdx.y * gridDim.x + blockIdx.x;
  lin = (lin & 7) * (nb >> 3) + (lin >> 3);
  const int m0 = (int)(lin / gridDim.x) * BM;
  const int n0 = (int)(lin % gridDim.x) * BN;

  f32x4 acc[4][4] = {};

  const int sr8    = lane >> 3;
  const int schunk = (lane & 7) ^ (sr8 & 7);
  const int fr  = lane & 15;
  const int fq  = lane >> 4;

  for (int k0 = 0; k0 < K; k0 += BKg) {
    __syncthreads();
#pragma unroll
    for (int i = 0; i < 4; ++i) {
      const int r = i * 32 + wid * 8 + sr8;
      gload_lds16(A + (size_t)(m0 + r) * K + k0 + schunk * 8,
                  (void*)(Al + (size_t)(i * 32 + wid * 8) * BKg));
      gload_lds16(Wb + (size_t)(n0 + r) * K + k0 + schunk * 8,
                  (void*)(Bl + (size_t)(i * 32 + wid * 8) * BKg));
    }
    __syncthreads();

#pragma unroll
    for (int kk = 0; kk < 2; ++kk) {
      bf16x8 af[4], bfr[4];
#pragma unroll
      for (int mi = 0; mi < 4; ++mi) {
        const int row = wr * 64 + mi * 16 + fr;
        const int ch  = (kk * 4 + fq) ^ (row & 7);
        af[mi] = *(const bf16x8*)(Al + (size_t)row * BKg + ch * 8);
      }
#pragma unroll
      for (int ni = 0; ni < 4; ++ni) {
        const int row = wc * 64 + ni * 16 + fr;
        const int ch  = (kk * 4 + fq) ^ (row & 7);
        bfr[ni] = *(const bf16x8*)(Bl + (size_t)row * BKg + ch * 8);
      }
#pragma unroll
      for (int mi = 0; mi < 4; ++mi)
#pragma unroll
        for (int ni = 0; ni < 4; ++ni)
          acc[mi][ni] = __builtin_amdgcn_mfma_f32_16x16x32_bf16(
              af[mi], bfr[ni], acc[mi][ni], 0, 0, 0);
    }
  }

  const int ecol  = fr;
  const int erow0 = fq * 4;
#pragma unroll
  for (int mi = 0; mi < 4; ++mi) {
#pragma unroll
    for (int r = 0; r < 4; ++r) {
      const int m = m0 + wr * 64 + mi * 16 + erow0 + r;
      size_t dstbase = 0;
      if (EPI == 2) {
        int w = m / NTOK_, tt = m - w * NTOK_;
        int bz = w >> 6, widx = w & 63;
        int wh = widx >> 3, ww = widx & 7;
        int ih = tt / WIN_, iw = tt - ih * WIN_;
        int gh = (wh * WIN_ + ih + SHIFT_) % H_;
        int gw = (ww * WIN_ + iw + SHIFT_) % W_;
        dstbase = ((size_t)bz * (H_ * W_) + gh * W_ + gw) * C_;
      }
#pragma unroll
      for (int ni = 0; ni < 4; ++ni) {
        const int n = n0 + wc * 64 + ni * 16 + ecol;
        float val = acc[mi][ni][r] + bias[n];
        if (EPI == 0) {
          ((unsigned short*)outv)[(size_t)m * Nn + n] = f2bf(val);
        } else {
          ((float*)outv)[dstbase + n] = resid[dstbase + n] + val;
        }
      }
    }
  }
}

// ---------------- Fused MLP: out += fc2( gelu( fc1(h2) ) ) ------------------
// 128 tokens/block, 8 waves. h2 A-frags in registers; 48 chunks of 32 hid
// cols: stage w1/w2 chunk (gload_lds, pre-swizzled src) -> FC1 MFMA -> gelu
// -> LDS -> FC2 MFMA into persistent acc. No hid round-trip to HBM.
__global__ __launch_bounds__(512, 2)
void fused_mlp_kernel(const unsigned short* __restrict__ h2,   // [T_,384] bf16
                      const unsigned short* __restrict__ w1b,  // [1536,384] bf16
                      const float* __restrict__ fc1_b,
                      const unsigned short* __restrict__ w2b,  // [384,1536] bf16
                      const float* __restrict__ fc2_b,
                      float* __restrict__ out) {               // [T_,384] f32, +=
  __shared__ unsigned short w1s[32 * 384];      // [32 hidcols][K=384], swizzled
  __shared__ unsigned short w2s[384 * 32];      // [384 outcols][KC=32], swizzled
  __shared__ unsigned short hidc[128 * 40];     // [128 rows][32+8]
  const int t    = threadIdx.x;
  const int wid  = t >> 6;     // 0..7
  const int lane = t & 63;
  const int c  = lane & 15;
  const int fq = lane >> 4;
  const int m0 = blockIdx.x * 128;

  // preload h2 fragments: wave owns token rows [16*wid, +16)
  bf16x8 aH[12];
#pragma unroll
  for (int ks = 0; ks < 12; ++ks)
    aH[ks] = ldg8(h2 + (size_t)(m0 + wid * 16 + c) * 384 + ks * 32 + fq * 8);

  f32x4 oacc[8][3] = {};

  for (int ck = 0; ck < 48; ++ck) {
    __syncthreads();                     // prev-chunk LDS reads complete
    // ---- stage w1 rows [32ck..+32) (24 KB) + w2 cols [32ck..+32) (24 KB) ----
#pragma unroll
    for (int ii = 0; ii < 3; ++ii) {
      const int i   = wid * 3 + ii;                 // 0..23
      const int byt = i * 1024 + lane * 16;
      const int row = byt / 768;                    // w1 row (0..31)
      const int rc  = (byt - row * 768) >> 4;       // dest chunk 0..47
      gload_lds16(w1b + (size_t)(ck * 32 + row) * 384 + ((rc ^ (row & 7)) * 8),
                  (void*)(w1s + i * 512));
    }
#pragma unroll
    for (int ii = 0; ii < 3; ++ii) {
      const int i   = wid * 3 + ii;
      const int row = i * 16 + (lane >> 2);         // w2 row 0..383
      const int cd  = lane & 3;
      gload_lds16(w2b + (size_t)row * MLP_ + ck * 32 + ((cd ^ (row & 3)) * 8),
                  (void*)(w2s + i * 512));
    }
    __syncthreads();                     // staged LDS visible

    // ---- FC1: S[16 rows][32 cols], K=384 (24 MFMA) ----
    f32x4 sacc[2] = {};
#pragma unroll
    for (int ks = 0; ks < 12; ++ks) {
#pragma unroll
      for (int ni = 0; ni < 2; ++ni) {
        const int row = ni * 16 + c;
        const int ch  = (ks * 4 + fq) ^ (row & 7);
        bf16x8 b = *(const bf16x8*)(w1s + row * 384 + ch * 8);
        sacc[ni] = __builtin_amdgcn_mfma_f32_16x16x32_bf16(aH[ks], b, sacc[ni], 0, 0, 0);
      }
    }
    // ---- bias + fast gelu -> hidc ----
#pragma unroll
    for (int ni = 0; ni < 2; ++ni)
#pragma unroll
      for (int r = 0; r < 4; ++r) {
        const int hcol = ni * 16 + c;
        const float v = sacc[ni][r] + fc1_b[ck * 32 + hcol];
        hidc[(wid * 16 + fq * 4 + r) * 40 + hcol] = f2bf(gelu_fast(v));
      }
    __syncthreads();                     // hidc visible to all waves

    // ---- FC2 partial: oacc += hidc[128,32] @ w2[384,32]^T (24 MFMA) ----
    bf16x8 aP[8];
#pragma unroll
    for (int mi = 0; mi < 8; ++mi)
      aP[mi] = *(const bf16x8*)(hidc + (mi * 16 + c) * 40 + fq * 8);
#pragma unroll
    for (int nj = 0; nj < 3; ++nj) {
      const int row = wid * 48 + nj * 16 + c;
      const int ch  = fq ^ (row & 3);
      bf16x8 b = *(const bf16x8*)(w2s + row * 32 + ch * 8);
#pragma unroll
      for (int mi = 0; mi < 8; ++mi)
        oacc[mi][nj] = __builtin_amdgcn_mfma_f32_16x16x32_bf16(aP[mi], b, oacc[mi][nj], 0, 0, 0);
    }
  }

  // ---- epilogue: d_out[m,n] += acc + fc2_b[n] ----
#pragma unroll
  for (int mi = 0; mi < 8; ++mi)
#pragma unroll
    for (int r = 0; r < 4; ++r) {
      const int m = m0 + mi * 16 + fq * 4 + r;
#pragma unroll
      for (int nj = 0; nj < 3; ++nj) {
        const int n = wid * 48 + nj * 16 + c;
        out[(size_t)m * C_ + n] += oacc[mi][nj][r] + fc2_b[n];
      }
    }
}

// ---------------- bias expansion: rel_bias[169,12] -> biasx[12][49][49] -----
__global__ __launch_bounds__(64)
void bias_expand_kernel(const float* __restrict__ rel_bias,
                        float* __restrict__ biasx) {
  const int hi = blockIdx.x;              // head*49 + i
  const int head = hi / NTOK_, i = hi - head * NTOK_;
  const int j = threadIdx.x;
  if (j < NTOK_) {
    const int ih = i / 7, iw = i - ih * 7;
    const int jh = j / 7, jw = j - jh * 7;
    const int ridx = (ih - jh + 6) * 13 + (iw - jw + 6);
    biasx[(size_t)hi * NTOK_ + j] = rel_bias[ridx * HEADS_ + head];
  }
}

// ---------------- MFMA windowed attention: one wave = (window, head) --------
#define AW 2
__global__ __launch_bounds__(64 * AW)
void attn_mfma_kernel(const unsigned short* __restrict__ qkv,  // [T_,1152] bf16
                      const float* __restrict__ biasx,         // [12][49][49]
                      unsigned short* __restrict__ out) {      // [T_,384] bf16
  __shared__ unsigned short sP[AW][64 * 72];   // P  (rows=i, cols=j), stride 72
  __shared__ unsigned short sVT[AW][32 * 72];  // V^T (rows=d, cols=j), stride 72
  const int wid  = threadIdx.x >> 6;
  const int lane = threadIdx.x & 63;
  const int task = blockIdx.x * AW + wid;
  const int w    = task / HEADS_;
  const int head = task - w * HEADS_;
  const int widx = w & 63;
  const int wh = widx >> 3, ww = widx & 7;
  const bool edge = (wh == 7) || (ww == 7);
  const int c  = lane & 15;
  const int fq = lane >> 4;
  unsigned short* Pl = sP[wid];
  unsigned short* Vl = sVT[wid];
  const unsigned short* qw = qkv + (size_t)w * NTOK_ * (3 * C_);

  u16x8 vv[4];
#pragma unroll
  for (int p = 0; p < 4; ++p)
    vv[p] = *(const u16x8*)(qw + (size_t)(p * 16 + c) * (3 * C_) + 2 * C_ + head * HD_ + fq * 8);

  bf16x8 aQ[4], bK[4];
#pragma unroll
  for (int mi = 0; mi < 4; ++mi)
    aQ[mi] = ldg8(qw + (size_t)(mi * 16 + c) * (3 * C_) + head * HD_ + fq * 8);
#pragma unroll
  for (int ni = 0; ni < 4; ++ni)
    bK[ni] = ldg8(qw + (size_t)(ni * 16 + c) * (3 * C_) + C_ + head * HD_ + fq * 8);

  const f32x4 zero4 = {0.f, 0.f, 0.f, 0.f};
  f32x4 accS[4][4];
#pragma unroll
  for (int mi = 0; mi < 4; ++mi)
#pragma unroll
    for (int ni = 0; ni < 4; ++ni)
      accS[mi][ni] = __builtin_amdgcn_mfma_f32_16x16x32_bf16(aQ[mi], bK[ni], zero4, 0, 0, 0);

#pragma unroll
  for (int p = 0; p < 4; ++p)
#pragma unroll
    for (int u = 0; u < 8; ++u)
      Vl[(fq * 8 + u) * 72 + p * 16 + c] = (unsigned short)vv[p][u];

  float rowinv[4][4];
  const float* bh = biasx + (size_t)head * (NTOK_ * NTOK_);
#pragma unroll
  for (int mi = 0; mi < 4; ++mi) {
#pragma unroll
    for (int r = 0; r < 4; ++r) {
      const int i  = mi * 16 + fq * 4 + r;
      const int ic = i < NTOK_ ? i : 0;
      const int ih = ic / 7, iw = ic - ih * 7;
      int li = 0;
      if (edge) {
        const int shi = wh * 7 + ih, swi = ww * 7 + iw;
        li = (shi < 49 ? 0 : (shi < 53 ? 1 : 2)) * 3 + (swi < 49 ? 0 : (swi < 53 ? 1 : 2));
      }
      float sv[4];
#pragma unroll
      for (int ni = 0; ni < 4; ++ni) {
        const int j  = ni * 16 + c;
        const int jc = j < NTOK_ ? j : 0;
        float s = accS[mi][ni][r] * 0.17677669529663687f + bh[ic * NTOK_ + jc];
        if (edge) {
          const int jh = jc / 7, jw = jc - jh * 7;
          const int shj = wh * 7 + jh, swj = ww * 7 + jw;
          const int lj = (shj < 49 ? 0 : (shj < 53 ? 1 : 2)) * 3 + (swj < 49 ? 0 : (swj < 53 ? 1 : 2));
          if (lj != li) s -= 100.f;
        }
        if (j >= NTOK_) s = -1e30f;
        sv[ni] = s;
      }
      float mx = fmaxf(fmaxf(sv[0], sv[1]), fmaxf(sv[2], sv[3]));
      mx = fmaxf(mx, __shfl_xor(mx, 1));
      mx = fmaxf(mx, __shfl_xor(mx, 2));
      mx = fmaxf(mx, __shfl_xor(mx, 4));
      mx = fmaxf(mx, __shfl_xor(mx, 8));
      const float e0 = __expf(sv[0] - mx), e1 = __expf(sv[1] - mx);
      const float e2 = __expf(sv[2] - mx), e3 = __expf(sv[3] - mx);
      float sm = e0 + e1 + e2 + e3;
      sm += __shfl_xor(sm, 1);
      sm += __shfl_xor(sm, 2);
      sm += __shfl_xor(sm, 4);
      sm += __shfl_xor(sm, 8);
      rowinv[mi][r] = 1.0f / sm;
      const int prow = i * 72;
      Pl[prow +  0 + c] = f2bf(e0);
      Pl[prow + 16 + c] = f2bf(e1);
      Pl[prow + 32 + c] = f2bf(e2);
      Pl[prow + 48 + c] = f2bf(e3);
    }
  }

  f32x4 accO[4][2] = {};
#pragma unroll
  for (int kk = 0; kk < 2; ++kk) {
    bf16x8 ap[4], bv[2];
#pragma unroll
    for (int mi = 0; mi < 4; ++mi)
      ap[mi] = __builtin_bit_cast(bf16x8,
          *(const u16x8*)(Pl + (mi * 16 + c) * 72 + kk * 32 + fq * 8));
#pragma unroll
    for (int nd = 0; nd < 2; ++nd)
      bv[nd] = __builtin_bit_cast(bf16x8,
          *(const u16x8*)(Vl + (nd * 16 + c) * 72 + kk * 32 + fq * 8));
#pragma unroll
    for (int mi = 0; mi < 4; ++mi)
#pragma unroll
      for (int nd = 0; nd < 2; ++nd)
        accO[mi][nd] = __builtin_amdgcn_mfma_f32_16x16x32_bf16(ap[mi], bv[nd], accO[mi][nd], 0, 0, 0);
  }

#pragma unroll
  for (int mi = 0; mi < 4; ++mi)
#pragma unroll
    for (int r = 0; r < 4; ++r) {
      const int i = mi * 16 + fq * 4 + r;
      if (i < NTOK_) {
        const float inv = rowinv[mi][r];
#pragma unroll
        for (int nd = 0; nd < 2; ++nd)
          out[(size_t)(w * NTOK_ + i) * C_ + head * HD_ + nd * 16 + c] =
              f2bf(accO[mi][nd][r] * inv);
      }
    }
}

// -----------------------------------------------------------------------------
extern "C" void kernel_launch(void* const* d_in, const int* in_sizes, int n_in,
                              void* d_out, int out_size, void* d_ws, size_t ws_size,
                              hipStream_t stream) {
  const float* x        = (const float*)d_in[0];
  const float* g1       = (const float*)d_in[1];
  const float* b1       = (const float*)d_in[2];
  const float* qkv_w    = (const float*)d_in[3];
  const float* qkv_b    = (const float*)d_in[4];
  const float* rel_bias = (const float*)d_in[5];
  const float* proj_w   = (const float*)d_in[6];
  const float* proj_b   = (const float*)d_in[7];
  const float* g2       = (const float*)d_in[8];
  const float* b2       = (const float*)d_in[9];
  const float* fc1_w    = (const float*)d_in[10];
  const float* fc1_b    = (const float*)d_in[11];
  const float* fc2_w    = (const float*)d_in[12];
  const float* fc2_b    = (const float*)d_in[13];
  float* out = (float*)d_out;

  char* ws = (char*)d_ws;
  // region A [0, 77,070,336): xw -> attn_out -> h2
  // region B [77,070,336, 308,412,416): qkvb (231 MB); no hid buffer anymore
  // weights zone (static, written once at start, read-only after):
  unsigned short* xw   = (unsigned short*)(ws);
  unsigned short* qkvb = (unsigned short*)(ws + 77070336);
  unsigned short* attn_out = xw;
  unsigned short* h2   = xw;
  unsigned short* qkv_wb  = (unsigned short*)(ws + 308412416); // 884,736 B
  unsigned short* proj_wb = (unsigned short*)(ws + 309297152); // 294,912 B
  float*          biasx   = (float*)(ws + 309592064);          // 115,248 B
  unsigned short* fc1_wb  = (unsigned short*)(ws + 309707312); // 1,179,648 B
  unsigned short* fc2_wb  = (unsigned short*)(ws + 310886960); // 1,179,648 B

  // 0. weight converts + bias expansion (all read-only source inputs)
  wconv_kernel<<<dim3(432), dim3(256), 0, stream>>>(qkv_w, qkv_wb, 3 * C_ * C_);
  wconv_kernel<<<dim3(144), dim3(256), 0, stream>>>(proj_w, proj_wb, C_ * C_);
  wconv_kernel<<<dim3(576), dim3(256), 0, stream>>>(fc1_w, fc1_wb, MLP_ * C_);
  wconv_kernel<<<dim3(576), dim3(256), 0, stream>>>(fc2_w, fc2_wb, C_ * MLP_);
  bias_expand_kernel<<<dim3(HEADS_ * NTOK_), dim3(64), 0, stream>>>(rel_bias, biasx);

  // 1. LN1 + shift + window partition -> xw (bf16, window layout)
  ln_kernel<1><<<dim3(T_ / 4), dim3(256), 0, stream>>>(x, g1, b1, xw);

  // 2. QKV GEMM: [T_,384] @ [1152,384]^T -> qkv (bf16)
  mfma_gemm<0><<<dim3(1152 / BN, T_ / BM), dim3(256), 0, stream>>>(
      xw, qkv_wb, qkv_b, (void*)qkvb, nullptr, T_, 1152, 384);

  // 3. MFMA windowed attention -> attn_out
  attn_mfma_kernel<<<dim3((T_ / NTOK_) * HEADS_ / AW), dim3(64 * AW), 0, stream>>>(
      qkvb, biasx, attn_out);

  // 4. proj GEMM + window-reverse + unshift + residual -> d_out = x1 (f32)
  mfma_gemm<2><<<dim3(384 / BN, T_ / BM), dim3(256), 0, stream>>>(
      attn_out, proj_wb, proj_b, (void*)out, x, T_, 384, 384);

  // 5. LN2 on x1 -> h2 (bf16)
  ln_kernel<0><<<dim3(T_ / 4), dim3(256), 0, stream>>>(out, g2, b2, h2);

  // 6. Fused MLP: d_out += fc2(gelu(fc1(h2)))
  fused_mlp_kernel<<<dim3(T_ / 128), dim3(512), 0, stream>>>(
      h2, fc1_wb, fc1_b, fc2_wb, fc2_b, out);
}

// Round 6
// 1152.237 us; speedup vs baseline: 1.0663x; 1.0663x over previous
//
#include <hip/hip_runtime.h>
#include <hip/hip_bf16.h>
#include <math.h>

#define B_      32
#define H_      56
#define W_      56
#define C_      384
#define HEADS_  12
#define WIN_    7
#define SHIFT_  3
#define NTOK_   49
#define HD_     32
#define T_      100352   // B_*H_*W_
#define MLP_    1536
#define TCH_    50176    // T_/2, MLP token chunk

typedef __bf16 bf16x8 __attribute__((ext_vector_type(8)));
typedef unsigned short u16x8 __attribute__((ext_vector_type(8)));
typedef float  f32x4  __attribute__((ext_vector_type(4)));

__device__ __forceinline__ float bf2f(unsigned short u) {
  union { unsigned int i; float f; } v; v.i = ((unsigned int)u) << 16; return v.f;
}
__device__ __forceinline__ unsigned short f2bf(float f) {
  union { float f; unsigned int i; } v; v.f = f;
  unsigned int x = v.i;
  return (unsigned short)((x + 0x7fffu + ((x >> 16) & 1u)) >> 16);
}
// fast tanh-GELU (max |err| ~1e-3 pre-FC2; negligible after 0.02-scale weights)
__device__ __forceinline__ float gelu_fast(float x) {
  const float t = 0.79788456f * x * (1.0f + 0.044715f * x * x);
  const float e = __expf(2.0f * t);
  const float th = 1.0f - 2.0f / (e + 1.0f);   // tanh(t), inf-safe
  return 0.5f * x * (1.0f + th);
}
__device__ __forceinline__ void gload_lds16(const void* g, void* l) {
  __builtin_amdgcn_global_load_lds(
      (const __attribute__((address_space(1))) void*)g,
      (__attribute__((address_space(3))) void*)l, 16, 0, 0);
}
__device__ __forceinline__ bf16x8 ldg8(const unsigned short* p) {
  u16x8 v = *(const u16x8*)p;
  return __builtin_bit_cast(bf16x8, v);
}

// ---------------- f32 -> bf16 weight convert (n divisible by 1024) ----------
__global__ __launch_bounds__(256)
void wconv_kernel(const float* __restrict__ src, unsigned short* __restrict__ dst, int n) {
  const int i = (blockIdx.x * 256 + threadIdx.x) * 4;
  if (i < n) {
    const float4 v = *(const float4*)(src + i);
    ushort4 o;
    o.x = f2bf(v.x); o.y = f2bf(v.y); o.z = f2bf(v.z); o.w = f2bf(v.w);
    *(ushort4*)(dst + i) = o;
  }
}

// ---------------- LayerNorm: 4 rows / 256-thread block ----------------------
template<int REMAP>
__global__ __launch_bounds__(256)
void ln_kernel(const float* __restrict__ xin, const float* __restrict__ g,
               const float* __restrict__ bb, unsigned short* __restrict__ outbf) {
  const int m = blockIdx.x * 4 + (threadIdx.x >> 6);
  const int lane = threadIdx.x & 63;
  size_t src;
  if (REMAP) {
    int w = m / NTOK_, t = m - w * NTOK_;
    int bz = w >> 6, widx = w & 63;
    int wh = widx >> 3, ww = widx & 7;
    int ih = t / WIN_, iw = t - ih * WIN_;
    int gh = (wh * WIN_ + ih + SHIFT_) % H_;
    int gw = (ww * WIN_ + iw + SHIFT_) % W_;
    src = ((size_t)bz * (H_ * W_) + gh * W_ + gw) * C_;
  } else {
    src = (size_t)m * C_;
  }
  const float* row = xin + src;
  float v[6]; float s = 0.f, s2 = 0.f;
#pragma unroll
  for (int u = 0; u < 6; ++u) {
    v[u] = row[lane + 64 * u];
    s += v[u]; s2 += v[u] * v[u];
  }
#pragma unroll
  for (int off = 32; off; off >>= 1) {
    s  += __shfl_xor(s, off);
    s2 += __shfl_xor(s2, off);
  }
  const float mean = s * (1.0f / C_);
  const float var  = s2 * (1.0f / C_) - mean * mean;
  const float rstd = rsqrtf(var + 1e-5f);
  unsigned short* orow = outbf + (size_t)m * C_;
#pragma unroll
  for (int u = 0; u < 6; ++u) {
    int c = lane + 64 * u;
    orow[c] = f2bf((v[u] - mean) * rstd * g[c] + bb[c]);
  }
}

// ---------------- MFMA GEMM: C[M,N] = A[M,K](bf16) @ W[N,K]^T(bf16) + bias --
// 128x128 tile, BK=64, 4 waves 2x2. A and B staged via global_load_lds with
// pre-swizzled source (chunk ^= row&7). XCD-chunked bijective block swizzle.
// EPI: 0 bf16; 1 fast-gelu->bf16; 2 window-reverse+unshift+resid ->f32; 3 f32 +=
#define BM 128
#define BN 128
#define BKg 64

template<int EPI>
__global__ __launch_bounds__(256)
void mfma_gemm(const unsigned short* __restrict__ A,   // [M,K] bf16
               const unsigned short* __restrict__ Wb,  // [N,K] bf16
               const float* __restrict__ bias,
               void* __restrict__ outv,
               const float* __restrict__ resid,
               int M, int Nn, int K) {
  __shared__ unsigned short Al[BM * BKg];
  __shared__ unsigned short Bl[BN * BKg];
  const int t    = threadIdx.x;
  const int wid  = t >> 6;
  const int lane = t & 63;
  const int wr   = wid >> 1, wc = wid & 1;

  const unsigned int nb = gridDim.x * gridDim.y;
  unsigned int lin = blockIdx.y * gridDim.x + blockIdx.x;
  lin = (lin & 7) * (nb >> 3) + (lin >> 3);
  const int m0 = (int)(lin / gridDim.x) * BM;
  const int n0 = (int)(lin % gridDim.x) * BN;

  f32x4 acc[4][4] = {};

  const int sr8    = lane >> 3;
  const int schunk = (lane & 7) ^ (sr8 & 7);
  const int fr  = lane & 15;
  const int fq  = lane >> 4;

  for (int k0 = 0; k0 < K; k0 += BKg) {
    __syncthreads();
#pragma unroll
    for (int i = 0; i < 4; ++i) {
      const int r = i * 32 + wid * 8 + sr8;
      gload_lds16(A + (size_t)(m0 + r) * K + k0 + schunk * 8,
                  (void*)(Al + (size_t)(i * 32 + wid * 8) * BKg));
      gload_lds16(Wb + (size_t)(n0 + r) * K + k0 + schunk * 8,
                  (void*)(Bl + (size_t)(i * 32 + wid * 8) * BKg));
    }
    __syncthreads();

#pragma unroll
    for (int kk = 0; kk < 2; ++kk) {
      bf16x8 af[4], bfr[4];
#pragma unroll
      for (int mi = 0; mi < 4; ++mi) {
        const int row = wr * 64 + mi * 16 + fr;
        const int ch  = (kk * 4 + fq) ^ (row & 7);
        af[mi] = *(const bf16x8*)(Al + (size_t)row * BKg + ch * 8);
      }
#pragma unroll
      for (int ni = 0; ni < 4; ++ni) {
        const int row = wc * 64 + ni * 16 + fr;
        const int ch  = (kk * 4 + fq) ^ (row & 7);
        bfr[ni] = *(const bf16x8*)(Bl + (size_t)row * BKg + ch * 8);
      }
#pragma unroll
      for (int mi = 0; mi < 4; ++mi)
#pragma unroll
        for (int ni = 0; ni < 4; ++ni)
          acc[mi][ni] = __builtin_amdgcn_mfma_f32_16x16x32_bf16(
              af[mi], bfr[ni], acc[mi][ni], 0, 0, 0);
    }
  }

  const int ecol  = fr;
  const int erow0 = fq * 4;
#pragma unroll
  for (int mi = 0; mi < 4; ++mi) {
#pragma unroll
    for (int r = 0; r < 4; ++r) {
      const int m = m0 + wr * 64 + mi * 16 + erow0 + r;
      size_t dstbase = 0;
      if (EPI == 2) {
        int w = m / NTOK_, tt = m - w * NTOK_;
        int bz = w >> 6, widx = w & 63;
        int wh = widx >> 3, ww = widx & 7;
        int ih = tt / WIN_, iw = tt - ih * WIN_;
        int gh = (wh * WIN_ + ih + SHIFT_) % H_;
        int gw = (ww * WIN_ + iw + SHIFT_) % W_;
        dstbase = ((size_t)bz * (H_ * W_) + gh * W_ + gw) * C_;
      }
#pragma unroll
      for (int ni = 0; ni < 4; ++ni) {
        const int n = n0 + wc * 64 + ni * 16 + ecol;
        float val = acc[mi][ni][r] + bias[n];
        if (EPI == 0) {
          ((unsigned short*)outv)[(size_t)m * Nn + n] = f2bf(val);
        } else if (EPI == 1) {
          ((unsigned short*)outv)[(size_t)m * Nn + n] = f2bf(gelu_fast(val));
        } else if (EPI == 2) {
          ((float*)outv)[dstbase + n] = resid[dstbase + n] + val;
        } else {
          float* o = (float*)outv + (size_t)m * Nn + n;
          *o += val;
        }
      }
    }
  }
}

// ---------------- bias expansion: rel_bias[169,12] -> biasx[12][49][49] -----
__global__ __launch_bounds__(64)
void bias_expand_kernel(const float* __restrict__ rel_bias,
                        float* __restrict__ biasx) {
  const int hi = blockIdx.x;              // head*49 + i
  const int head = hi / NTOK_, i = hi - head * NTOK_;
  const int j = threadIdx.x;
  if (j < NTOK_) {
    const int ih = i / 7, iw = i - ih * 7;
    const int jh = j / 7, jw = j - jh * 7;
    const int ridx = (ih - jh + 6) * 13 + (iw - jw + 6);
    biasx[(size_t)hi * NTOK_ + j] = rel_bias[ridx * HEADS_ + head];
  }
}

// ---------------- MFMA windowed attention: one wave = (window, head) --------
#define AW 2
__global__ __launch_bounds__(64 * AW)
void attn_mfma_kernel(const unsigned short* __restrict__ qkv,  // [T_,1152] bf16
                      const float* __restrict__ biasx,         // [12][49][49]
                      unsigned short* __restrict__ out) {      // [T_,384] bf16
  __shared__ unsigned short sP[AW][64 * 72];   // P  (rows=i, cols=j), stride 72
  __shared__ unsigned short sVT[AW][32 * 72];  // V^T (rows=d, cols=j), stride 72
  const int wid  = threadIdx.x >> 6;
  const int lane = threadIdx.x & 63;
  const int task = blockIdx.x * AW + wid;
  const int w    = task / HEADS_;
  const int head = task - w * HEADS_;
  const int widx = w & 63;
  const int wh = widx >> 3, ww = widx & 7;
  const bool edge = (wh == 7) || (ww == 7);
  const int c  = lane & 15;
  const int fq = lane >> 4;
  unsigned short* Pl = sP[wid];
  unsigned short* Vl = sVT[wid];
  const unsigned short* qw = qkv + (size_t)w * NTOK_ * (3 * C_);

  u16x8 vv[4];
#pragma unroll
  for (int p = 0; p < 4; ++p)
    vv[p] = *(const u16x8*)(qw + (size_t)(p * 16 + c) * (3 * C_) + 2 * C_ + head * HD_ + fq * 8);

  bf16x8 aQ[4], bK[4];
#pragma unroll
  for (int mi = 0; mi < 4; ++mi)
    aQ[mi] = ldg8(qw + (size_t)(mi * 16 + c) * (3 * C_) + head * HD_ + fq * 8);
#pragma unroll
  for (int ni = 0; ni < 4; ++ni)
    bK[ni] = ldg8(qw + (size_t)(ni * 16 + c) * (3 * C_) + C_ + head * HD_ + fq * 8);

  const f32x4 zero4 = {0.f, 0.f, 0.f, 0.f};
  f32x4 accS[4][4];
#pragma unroll
  for (int mi = 0; mi < 4; ++mi)
#pragma unroll
    for (int ni = 0; ni < 4; ++ni)
      accS[mi][ni] = __builtin_amdgcn_mfma_f32_16x16x32_bf16(aQ[mi], bK[ni], zero4, 0, 0, 0);

#pragma unroll
  for (int p = 0; p < 4; ++p)
#pragma unroll
    for (int u = 0; u < 8; ++u)
      Vl[(fq * 8 + u) * 72 + p * 16 + c] = (unsigned short)vv[p][u];

  float rowinv[4][4];
  const float* bh = biasx + (size_t)head * (NTOK_ * NTOK_);
#pragma unroll
  for (int mi = 0; mi < 4; ++mi) {
#pragma unroll
    for (int r = 0; r < 4; ++r) {
      const int i  = mi * 16 + fq * 4 + r;
      const int ic = i < NTOK_ ? i : 0;
      const int ih = ic / 7, iw = ic - ih * 7;
      int li = 0;
      if (edge) {
        const int shi = wh * 7 + ih, swi = ww * 7 + iw;
        li = (shi < 49 ? 0 : (shi < 53 ? 1 : 2)) * 3 + (swi < 49 ? 0 : (swi < 53 ? 1 : 2));
      }
      float sv[4];
#pragma unroll
      for (int ni = 0; ni < 4; ++ni) {
        const int j  = ni * 16 + c;
        const int jc = j < NTOK_ ? j : 0;
        float s = accS[mi][ni][r] * 0.17677669529663687f + bh[ic * NTOK_ + jc];
        if (edge) {
          const int jh = jc / 7, jw = jc - jh * 7;
          const int shj = wh * 7 + jh, swj = ww * 7 + jw;
          const int lj = (shj < 49 ? 0 : (shj < 53 ? 1 : 2)) * 3 + (swj < 49 ? 0 : (swj < 53 ? 1 : 2));
          if (lj != li) s -= 100.f;
        }
        if (j >= NTOK_) s = -1e30f;
        sv[ni] = s;
      }
      float mx = fmaxf(fmaxf(sv[0], sv[1]), fmaxf(sv[2], sv[3]));
      mx = fmaxf(mx, __shfl_xor(mx, 1));
      mx = fmaxf(mx, __shfl_xor(mx, 2));
      mx = fmaxf(mx, __shfl_xor(mx, 4));
      mx = fmaxf(mx, __shfl_xor(mx, 8));
      const float e0 = __expf(sv[0] - mx), e1 = __expf(sv[1] - mx);
      const float e2 = __expf(sv[2] - mx), e3 = __expf(sv[3] - mx);
      float sm = e0 + e1 + e2 + e3;
      sm += __shfl_xor(sm, 1);
      sm += __shfl_xor(sm, 2);
      sm += __shfl_xor(sm, 4);
      sm += __shfl_xor(sm, 8);
      rowinv[mi][r] = 1.0f / sm;
      const int prow = i * 72;
      Pl[prow +  0 + c] = f2bf(e0);
      Pl[prow + 16 + c] = f2bf(e1);
      Pl[prow + 32 + c] = f2bf(e2);
      Pl[prow + 48 + c] = f2bf(e3);
    }
  }

  f32x4 accO[4][2] = {};
#pragma unroll
  for (int kk = 0; kk < 2; ++kk) {
    bf16x8 ap[4], bv[2];
#pragma unroll
    for (int mi = 0; mi < 4; ++mi)
      ap[mi] = __builtin_bit_cast(bf16x8,
          *(const u16x8*)(Pl + (mi * 16 + c) * 72 + kk * 32 + fq * 8));
#pragma unroll
    for (int nd = 0; nd < 2; ++nd)
      bv[nd] = __builtin_bit_cast(bf16x8,
          *(const u16x8*)(Vl + (nd * 16 + c) * 72 + kk * 32 + fq * 8));
#pragma unroll
    for (int mi = 0; mi < 4; ++mi)
#pragma unroll
      for (int nd = 0; nd < 2; ++nd)
        accO[mi][nd] = __builtin_amdgcn_mfma_f32_16x16x32_bf16(ap[mi], bv[nd], accO[mi][nd], 0, 0, 0);
  }

#pragma unroll
  for (int mi = 0; mi < 4; ++mi)
#pragma unroll
    for (int r = 0; r < 4; ++r) {
      const int i = mi * 16 + fq * 4 + r;
      if (i < NTOK_) {
        const float inv = rowinv[mi][r];
#pragma unroll
        for (int nd = 0; nd < 2; ++nd)
          out[(size_t)(w * NTOK_ + i) * C_ + head * HD_ + nd * 16 + c] =
              f2bf(accO[mi][nd][r] * inv);
      }
    }
}

// -----------------------------------------------------------------------------
extern "C" void kernel_launch(void* const* d_in, const int* in_sizes, int n_in,
                              void* d_out, int out_size, void* d_ws, size_t ws_size,
                              hipStream_t stream) {
  const float* x        = (const float*)d_in[0];
  const float* g1       = (const float*)d_in[1];
  const float* b1       = (const float*)d_in[2];
  const float* qkv_w    = (const float*)d_in[3];
  const float* qkv_b    = (const float*)d_in[4];
  const float* rel_bias = (const float*)d_in[5];
  const float* proj_w   = (const float*)d_in[6];
  const float* proj_b   = (const float*)d_in[7];
  const float* g2       = (const float*)d_in[8];
  const float* b2       = (const float*)d_in[9];
  const float* fc1_w    = (const float*)d_in[10];
  const float* fc1_b    = (const float*)d_in[11];
  const float* fc2_w    = (const float*)d_in[12];
  const float* fc2_b    = (const float*)d_in[13];
  float* out = (float*)d_out;

  char* ws = (char*)d_ws;
  // region A [0, 77,070,336): xw -> attn_out -> h2
  // region B [77,070,336, 308,281,344): qkvb (231 MB); after attn, reused as
  //   hid_chunk (TCH_*1536*2 = 154,140,672 B at [77,070,336, 231,211,008))
  // weights zone [308,412,416, 312,066,608): static, written once, read-only;
  //   never overlapped by hid_chunk (ends at 231,211,008).
  unsigned short* xw   = (unsigned short*)(ws);
  unsigned short* qkvb = (unsigned short*)(ws + 77070336);
  unsigned short* attn_out = xw;
  unsigned short* h2   = xw;
  unsigned short* hidc = qkvb;                                 // chunk buffer
  unsigned short* qkv_wb  = (unsigned short*)(ws + 308412416); // 884,736 B
  unsigned short* proj_wb = (unsigned short*)(ws + 309297152); // 294,912 B
  float*          biasx   = (float*)(ws + 309592064);          // 115,248 B
  unsigned short* fc1_wb  = (unsigned short*)(ws + 309707312); // 1,179,648 B
  unsigned short* fc2_wb  = (unsigned short*)(ws + 310886960); // 1,179,648 B

  // 0. weight converts + bias expansion (read-only sources; zone is static)
  wconv_kernel<<<dim3(432), dim3(256), 0, stream>>>(qkv_w, qkv_wb, 3 * C_ * C_);
  wconv_kernel<<<dim3(144), dim3(256), 0, stream>>>(proj_w, proj_wb, C_ * C_);
  wconv_kernel<<<dim3(576), dim3(256), 0, stream>>>(fc1_w, fc1_wb, MLP_ * C_);
  wconv_kernel<<<dim3(576), dim3(256), 0, stream>>>(fc2_w, fc2_wb, C_ * MLP_);
  bias_expand_kernel<<<dim3(HEADS_ * NTOK_), dim3(64), 0, stream>>>(rel_bias, biasx);

  // 1. LN1 + shift + window partition -> xw (bf16, window layout)
  ln_kernel<1><<<dim3(T_ / 4), dim3(256), 0, stream>>>(x, g1, b1, xw);

  // 2. QKV GEMM: [T_,384] @ [1152,384]^T -> qkv (bf16)
  mfma_gemm<0><<<dim3(1152 / BN, T_ / BM), dim3(256), 0, stream>>>(
      xw, qkv_wb, qkv_b, (void*)qkvb, nullptr, T_, 1152, 384);

  // 3. MFMA windowed attention -> attn_out
  attn_mfma_kernel<<<dim3((T_ / NTOK_) * HEADS_ / AW), dim3(64 * AW), 0, stream>>>(
      qkvb, biasx, attn_out);

  // 4. proj GEMM + window-reverse + unshift + residual -> d_out = x1 (f32)
  mfma_gemm<2><<<dim3(384 / BN, T_ / BM), dim3(256), 0, stream>>>(
      attn_out, proj_wb, proj_b, (void*)out, x, T_, 384, 384);

  // 5. LN2 on x1 -> h2 (bf16)
  ln_kernel<0><<<dim3(T_ / 4), dim3(256), 0, stream>>>(out, g2, b2, h2);

  // 6. MLP in 2 token-chunks (hid_chunk fits below the weight zone):
  //    FC1: h2[c] @ fc1^T -> gelu -> hidc;  FC2: d_out[c] += hidc @ fc2^T
  for (int chk = 0; chk < 2; ++chk) {
    const size_t row0 = (size_t)chk * TCH_;
    mfma_gemm<1><<<dim3(MLP_ / BN, TCH_ / BM), dim3(256), 0, stream>>>(
        h2 + row0 * C_, fc1_wb, fc1_b, (void*)hidc, nullptr, TCH_, MLP_, 384);
    mfma_gemm<3><<<dim3(384 / BN, TCH_ / BM), dim3(256), 0, stream>>>(
        hidc, fc2_wb, fc2_b, (void*)(out + row0 * C_), nullptr, TCH_, 384, MLP_);
  }
}

// Round 7
// 1124.878 us; speedup vs baseline: 1.0922x; 1.0243x over previous
//
#include <hip/hip_runtime.h>
#include <hip/hip_bf16.h>
#include <math.h>

#define B_      32
#define H_      56
#define W_      56
#define C_      384
#define HEADS_  12
#define WIN_    7
#define SHIFT_  3
#define NTOK_   49
#define HD_     32
#define T_      100352   // B_*H_*W_
#define MLP_    1536
#define TCH_    50176    // T_/2, MLP token chunk

typedef __bf16 bf16x8 __attribute__((ext_vector_type(8)));
typedef unsigned short u16x8 __attribute__((ext_vector_type(8)));
typedef float  f32x4  __attribute__((ext_vector_type(4)));

__device__ __forceinline__ float bf2f(unsigned short u) {
  union { unsigned int i; float f; } v; v.i = ((unsigned int)u) << 16; return v.f;
}
__device__ __forceinline__ unsigned short f2bf(float f) {
  union { float f; unsigned int i; } v; v.f = f;
  unsigned int x = v.i;
  return (unsigned short)((x + 0x7fffu + ((x >> 16) & 1u)) >> 16);
}
// fast tanh-GELU (max |err| ~1e-3 pre-FC2; negligible after 0.02-scale weights)
__device__ __forceinline__ float gelu_fast(float x) {
  const float t = 0.79788456f * x * (1.0f + 0.044715f * x * x);
  const float e = __expf(2.0f * t);
  const float th = 1.0f - 2.0f / (e + 1.0f);   // tanh(t), inf-safe
  return 0.5f * x * (1.0f + th);
}
__device__ __forceinline__ void gload_lds16(const void* g, void* l) {
  __builtin_amdgcn_global_load_lds(
      (const __attribute__((address_space(1))) void*)g,
      (__attribute__((address_space(3))) void*)l, 16, 0, 0);
}
__device__ __forceinline__ bf16x8 ldg8(const unsigned short* p) {
  u16x8 v = *(const u16x8*)p;
  return __builtin_bit_cast(bf16x8, v);
}

// ---------------- f32 -> bf16 weight convert (n divisible by 1024) ----------
__global__ __launch_bounds__(256)
void wconv_kernel(const float* __restrict__ src, unsigned short* __restrict__ dst, int n) {
  const int i = (blockIdx.x * 256 + threadIdx.x) * 4;
  if (i < n) {
    const float4 v = *(const float4*)(src + i);
    ushort4 o;
    o.x = f2bf(v.x); o.y = f2bf(v.y); o.z = f2bf(v.z); o.w = f2bf(v.w);
    *(ushort4*)(dst + i) = o;
  }
}

// ---------------- LayerNorm: 4 rows / 256-thread block ----------------------
template<int REMAP>
__global__ __launch_bounds__(256)
void ln_kernel(const float* __restrict__ xin, const float* __restrict__ g,
               const float* __restrict__ bb, unsigned short* __restrict__ outbf) {
  const int m = blockIdx.x * 4 + (threadIdx.x >> 6);
  const int lane = threadIdx.x & 63;
  size_t src;
  if (REMAP) {
    int w = m / NTOK_, t = m - w * NTOK_;
    int bz = w >> 6, widx = w & 63;
    int wh = widx >> 3, ww = widx & 7;
    int ih = t / WIN_, iw = t - ih * WIN_;
    int gh = (wh * WIN_ + ih + SHIFT_) % H_;
    int gw = (ww * WIN_ + iw + SHIFT_) % W_;
    src = ((size_t)bz * (H_ * W_) + gh * W_ + gw) * C_;
  } else {
    src = (size_t)m * C_;
  }
  const float* row = xin + src;
  float v[6]; float s = 0.f, s2 = 0.f;
#pragma unroll
  for (int u = 0; u < 6; ++u) {
    v[u] = row[lane + 64 * u];
    s += v[u]; s2 += v[u] * v[u];
  }
#pragma unroll
  for (int off = 32; off; off >>= 1) {
    s  += __shfl_xor(s, off);
    s2 += __shfl_xor(s2, off);
  }
  const float mean = s * (1.0f / C_);
  const float var  = s2 * (1.0f / C_) - mean * mean;
  const float rstd = rsqrtf(var + 1e-5f);
  unsigned short* orow = outbf + (size_t)m * C_;
#pragma unroll
  for (int u = 0; u < 6; ++u) {
    int c = lane + 64 * u;
    orow[c] = f2bf((v[u] - mean) * rstd * g[c] + bb[c]);
  }
}

// ---------------- MFMA GEMM: C[M,N] = A[M,K](bf16) @ W[N,K]^T(bf16) + bias --
// 128x128 tile, BK=64, 4 waves 2x2. DOUBLE-BUFFERED LDS + stage-early +
// counted vmcnt(8) + raw s_barrier: next tile's 8 global_load_lds stay in
// flight across the barrier while current tile computes (T3/T4-minimal).
// EPI: 0 bf16; 1 fast-gelu->bf16; 2 window-reverse+unshift+resid ->f32; 3 f32 +=
#define BM 128
#define BN 128
#define BKg 64

template<int EPI>
__global__ __launch_bounds__(256)
void mfma_gemm(const unsigned short* __restrict__ A,   // [M,K] bf16
               const unsigned short* __restrict__ Wb,  // [N,K] bf16
               const float* __restrict__ bias,
               void* __restrict__ outv,
               const float* __restrict__ resid,
               int M, int Nn, int K) {
  __shared__ unsigned short Al[2][BM * BKg];
  __shared__ unsigned short Bl[2][BM * BKg];
  const int t    = threadIdx.x;
  const int wid  = t >> 6;
  const int lane = t & 63;
  const int wr   = wid >> 1, wc = wid & 1;

  const unsigned int nb = gridDim.x * gridDim.y;
  unsigned int lin = blockIdx.y * gridDim.x + blockIdx.x;
  lin = (lin & 7) * (nb >> 3) + (lin >> 3);
  const int m0 = (int)(lin / gridDim.x) * BM;
  const int n0 = (int)(lin % gridDim.x) * BN;

  f32x4 acc[4][4] = {};

  const int sr8    = lane >> 3;
  const int schunk = (lane & 7) ^ (sr8 & 7);
  const int fr  = lane & 15;
  const int fq  = lane >> 4;

  const int nk = K / BKg;

  // stage K-step ks into buffer buf: 8 global_load_lds per thread (4 A + 4 B)
#define STAGE_(ks, buf)                                                        \
  {                                                                            \
    const int k0_ = (ks) * BKg;                                                \
    _Pragma("unroll")                                                          \
    for (int i = 0; i < 4; ++i) {                                              \
      const int r = i * 32 + wid * 8 + sr8;                                    \
      gload_lds16(A + (size_t)(m0 + r) * K + k0_ + schunk * 8,                 \
                  (void*)(&Al[buf][(i * 32 + wid * 8) * BKg]));                \
      gload_lds16(Wb + (size_t)(n0 + r) * K + k0_ + schunk * 8,                \
                  (void*)(&Bl[buf][(i * 32 + wid * 8) * BKg]));                \
    }                                                                          \
  }

  STAGE_(0, 0);
  int cur = 0;

  for (int ks = 0; ks < nk; ++ks) {
    if (ks + 1 < nk) {
      STAGE_(ks + 1, cur ^ 1);                       // issue next tile early
      asm volatile("s_waitcnt vmcnt(8)" ::: "memory"); // cur tile landed; next in flight
    } else {
      asm volatile("s_waitcnt vmcnt(0)" ::: "memory");
    }
    __builtin_amdgcn_sched_barrier(0);
    __builtin_amdgcn_s_barrier();                    // raw: no auto vmcnt(0) drain
    __builtin_amdgcn_sched_barrier(0);

    const unsigned short* Ab = &Al[cur][0];
    const unsigned short* Bb = &Bl[cur][0];
#pragma unroll
    for (int kk = 0; kk < 2; ++kk) {
      bf16x8 af[4], bfr[4];
#pragma unroll
      for (int mi = 0; mi < 4; ++mi) {
        const int row = wr * 64 + mi * 16 + fr;
        const int ch  = (kk * 4 + fq) ^ (row & 7);
        af[mi] = *(const bf16x8*)(Ab + (size_t)row * BKg + ch * 8);
      }
#pragma unroll
      for (int ni = 0; ni < 4; ++ni) {
        const int row = wc * 64 + ni * 16 + fr;
        const int ch  = (kk * 4 + fq) ^ (row & 7);
        bfr[ni] = *(const bf16x8*)(Bb + (size_t)row * BKg + ch * 8);
      }
#pragma unroll
      for (int mi = 0; mi < 4; ++mi)
#pragma unroll
        for (int ni = 0; ni < 4; ++ni)
          acc[mi][ni] = __builtin_amdgcn_mfma_f32_16x16x32_bf16(
              af[mi], bfr[ni], acc[mi][ni], 0, 0, 0);
    }

    __builtin_amdgcn_sched_barrier(0);
    __builtin_amdgcn_s_barrier();   // all waves done reading buf cur before re-stage
    __builtin_amdgcn_sched_barrier(0);
    cur ^= 1;
  }
#undef STAGE_

  const int ecol  = fr;
  const int erow0 = fq * 4;
#pragma unroll
  for (int mi = 0; mi < 4; ++mi) {
#pragma unroll
    for (int r = 0; r < 4; ++r) {
      const int m = m0 + wr * 64 + mi * 16 + erow0 + r;
      size_t dstbase = 0;
      if (EPI == 2) {
        int w = m / NTOK_, tt = m - w * NTOK_;
        int bz = w >> 6, widx = w & 63;
        int wh = widx >> 3, ww = widx & 7;
        int ih = tt / WIN_, iw = tt - ih * WIN_;
        int gh = (wh * WIN_ + ih + SHIFT_) % H_;
        int gw = (ww * WIN_ + iw + SHIFT_) % W_;
        dstbase = ((size_t)bz * (H_ * W_) + gh * W_ + gw) * C_;
      }
#pragma unroll
      for (int ni = 0; ni < 4; ++ni) {
        const int n = n0 + wc * 64 + ni * 16 + ecol;
        float val = acc[mi][ni][r] + bias[n];
        if (EPI == 0) {
          ((unsigned short*)outv)[(size_t)m * Nn + n] = f2bf(val);
        } else if (EPI == 1) {
          ((unsigned short*)outv)[(size_t)m * Nn + n] = f2bf(gelu_fast(val));
        } else if (EPI == 2) {
          ((float*)outv)[dstbase + n] = resid[dstbase + n] + val;
        } else {
          float* o = (float*)outv + (size_t)m * Nn + n;
          *o += val;
        }
      }
    }
  }
}

// ---------------- bias expansion: rel_bias[169,12] -> biasx[12][49][49] -----
__global__ __launch_bounds__(64)
void bias_expand_kernel(const float* __restrict__ rel_bias,
                        float* __restrict__ biasx) {
  const int hi = blockIdx.x;              // head*49 + i
  const int head = hi / NTOK_, i = hi - head * NTOK_;
  const int j = threadIdx.x;
  if (j < NTOK_) {
    const int ih = i / 7, iw = i - ih * 7;
    const int jh = j / 7, jw = j - jh * 7;
    const int ridx = (ih - jh + 6) * 13 + (iw - jw + 6);
    biasx[(size_t)hi * NTOK_ + j] = rel_bias[ridx * HEADS_ + head];
  }
}

// ---------------- MFMA windowed attention: one wave = (window, head) --------
#define AW 2
__global__ __launch_bounds__(64 * AW)
void attn_mfma_kernel(const unsigned short* __restrict__ qkv,  // [T_,1152] bf16
                      const float* __restrict__ biasx,         // [12][49][49]
                      unsigned short* __restrict__ out) {      // [T_,384] bf16
  __shared__ unsigned short sP[AW][64 * 72];   // P  (rows=i, cols=j), stride 72
  __shared__ unsigned short sVT[AW][32 * 72];  // V^T (rows=d, cols=j), stride 72
  const int wid  = threadIdx.x >> 6;
  const int lane = threadIdx.x & 63;
  const int task = blockIdx.x * AW + wid;
  const int w    = task / HEADS_;
  const int head = task - w * HEADS_;
  const int widx = w & 63;
  const int wh = widx >> 3, ww = widx & 7;
  const bool edge = (wh == 7) || (ww == 7);
  const int c  = lane & 15;
  const int fq = lane >> 4;
  unsigned short* Pl = sP[wid];
  unsigned short* Vl = sVT[wid];
  const unsigned short* qw = qkv + (size_t)w * NTOK_ * (3 * C_);

  u16x8 vv[4];
#pragma unroll
  for (int p = 0; p < 4; ++p)
    vv[p] = *(const u16x8*)(qw + (size_t)(p * 16 + c) * (3 * C_) + 2 * C_ + head * HD_ + fq * 8);

  bf16x8 aQ[4], bK[4];
#pragma unroll
  for (int mi = 0; mi < 4; ++mi)
    aQ[mi] = ldg8(qw + (size_t)(mi * 16 + c) * (3 * C_) + head * HD_ + fq * 8);
#pragma unroll
  for (int ni = 0; ni < 4; ++ni)
    bK[ni] = ldg8(qw + (size_t)(ni * 16 + c) * (3 * C_) + C_ + head * HD_ + fq * 8);

  const f32x4 zero4 = {0.f, 0.f, 0.f, 0.f};
  f32x4 accS[4][4];
#pragma unroll
  for (int mi = 0; mi < 4; ++mi)
#pragma unroll
    for (int ni = 0; ni < 4; ++ni)
      accS[mi][ni] = __builtin_amdgcn_mfma_f32_16x16x32_bf16(aQ[mi], bK[ni], zero4, 0, 0, 0);

#pragma unroll
  for (int p = 0; p < 4; ++p)
#pragma unroll
    for (int u = 0; u < 8; ++u)
      Vl[(fq * 8 + u) * 72 + p * 16 + c] = (unsigned short)vv[p][u];

  float rowinv[4][4];
  const float* bh = biasx + (size_t)head * (NTOK_ * NTOK_);
#pragma unroll
  for (int mi = 0; mi < 4; ++mi) {
#pragma unroll
    for (int r = 0; r < 4; ++r) {
      const int i  = mi * 16 + fq * 4 + r;
      const int ic = i < NTOK_ ? i : 0;
      const int ih = ic / 7, iw = ic - ih * 7;
      int li = 0;
      if (edge) {
        const int shi = wh * 7 + ih, swi = ww * 7 + iw;
        li = (shi < 49 ? 0 : (shi < 53 ? 1 : 2)) * 3 + (swi < 49 ? 0 : (swi < 53 ? 1 : 2));
      }
      float sv[4];
#pragma unroll
      for (int ni = 0; ni < 4; ++ni) {
        const int j  = ni * 16 + c;
        const int jc = j < NTOK_ ? j : 0;
        float s = accS[mi][ni][r] * 0.17677669529663687f + bh[ic * NTOK_ + jc];
        if (edge) {
          const int jh = jc / 7, jw = jc - jh * 7;
          const int shj = wh * 7 + jh, swj = ww * 7 + jw;
          const int lj = (shj < 49 ? 0 : (shj < 53 ? 1 : 2)) * 3 + (swj < 49 ? 0 : (swj < 53 ? 1 : 2));
          if (lj != li) s -= 100.f;
        }
        if (j >= NTOK_) s = -1e30f;
        sv[ni] = s;
      }
      float mx = fmaxf(fmaxf(sv[0], sv[1]), fmaxf(sv[2], sv[3]));
      mx = fmaxf(mx, __shfl_xor(mx, 1));
      mx = fmaxf(mx, __shfl_xor(mx, 2));
      mx = fmaxf(mx, __shfl_xor(mx, 4));
      mx = fmaxf(mx, __shfl_xor(mx, 8));
      const float e0 = __expf(sv[0] - mx), e1 = __expf(sv[1] - mx);
      const float e2 = __expf(sv[2] - mx), e3 = __expf(sv[3] - mx);
      float sm = e0 + e1 + e2 + e3;
      sm += __shfl_xor(sm, 1);
      sm += __shfl_xor(sm, 2);
      sm += __shfl_xor(sm, 4);
      sm += __shfl_xor(sm, 8);
      rowinv[mi][r] = 1.0f / sm;
      const int prow = i * 72;
      Pl[prow +  0 + c] = f2bf(e0);
      Pl[prow + 16 + c] = f2bf(e1);
      Pl[prow + 32 + c] = f2bf(e2);
      Pl[prow + 48 + c] = f2bf(e3);
    }
  }

  f32x4 accO[4][2] = {};
#pragma unroll
  for (int kk = 0; kk < 2; ++kk) {
    bf16x8 ap[4], bv[2];
#pragma unroll
    for (int mi = 0; mi < 4; ++mi)
      ap[mi] = __builtin_bit_cast(bf16x8,
          *(const u16x8*)(Pl + (mi * 16 + c) * 72 + kk * 32 + fq * 8));
#pragma unroll
    for (int nd = 0; nd < 2; ++nd)
      bv[nd] = __builtin_bit_cast(bf16x8,
          *(const u16x8*)(Vl + (nd * 16 + c) * 72 + kk * 32 + fq * 8));
#pragma unroll
    for (int mi = 0; mi < 4; ++mi)
#pragma unroll
      for (int nd = 0; nd < 2; ++nd)
        accO[mi][nd] = __builtin_amdgcn_mfma_f32_16x16x32_bf16(ap[mi], bv[nd], accO[mi][nd], 0, 0, 0);
  }

#pragma unroll
  for (int mi = 0; mi < 4; ++mi)
#pragma unroll
    for (int r = 0; r < 4; ++r) {
      const int i = mi * 16 + fq * 4 + r;
      if (i < NTOK_) {
        const float inv = rowinv[mi][r];
#pragma unroll
        for (int nd = 0; nd < 2; ++nd)
          out[(size_t)(w * NTOK_ + i) * C_ + head * HD_ + nd * 16 + c] =
              f2bf(accO[mi][nd][r] * inv);
      }
    }
}

// -----------------------------------------------------------------------------
extern "C" void kernel_launch(void* const* d_in, const int* in_sizes, int n_in,
                              void* d_out, int out_size, void* d_ws, size_t ws_size,
                              hipStream_t stream) {
  const float* x        = (const float*)d_in[0];
  const float* g1       = (const float*)d_in[1];
  const float* b1       = (const float*)d_in[2];
  const float* qkv_w    = (const float*)d_in[3];
  const float* qkv_b    = (const float*)d_in[4];
  const float* rel_bias = (const float*)d_in[5];
  const float* proj_w   = (const float*)d_in[6];
  const float* proj_b   = (const float*)d_in[7];
  const float* g2       = (const float*)d_in[8];
  const float* b2       = (const float*)d_in[9];
  const float* fc1_w    = (const float*)d_in[10];
  const float* fc1_b    = (const float*)d_in[11];
  const float* fc2_w    = (const float*)d_in[12];
  const float* fc2_b    = (const float*)d_in[13];
  float* out = (float*)d_out;

  char* ws = (char*)d_ws;
  // region A [0, 77,070,336): xw -> attn_out -> h2
  // region B [77,070,336, 308,281,344): qkvb (231 MB); after attn, reused as
  //   hid_chunk (TCH_*1536*2 = 154,140,672 B at [77,070,336, 231,211,008))
  // weights zone [308,412,416, 312,066,608): static, written once, read-only.
  unsigned short* xw   = (unsigned short*)(ws);
  unsigned short* qkvb = (unsigned short*)(ws + 77070336);
  unsigned short* attn_out = xw;
  unsigned short* h2   = xw;
  unsigned short* hidc = qkvb;                                 // chunk buffer
  unsigned short* qkv_wb  = (unsigned short*)(ws + 308412416); // 884,736 B
  unsigned short* proj_wb = (unsigned short*)(ws + 309297152); // 294,912 B
  float*          biasx   = (float*)(ws + 309592064);          // 115,248 B
  unsigned short* fc1_wb  = (unsigned short*)(ws + 309707312); // 1,179,648 B
  unsigned short* fc2_wb  = (unsigned short*)(ws + 310886960); // 1,179,648 B

  // 0. weight converts + bias expansion (read-only sources; zone is static)
  wconv_kernel<<<dim3(432), dim3(256), 0, stream>>>(qkv_w, qkv_wb, 3 * C_ * C_);
  wconv_kernel<<<dim3(144), dim3(256), 0, stream>>>(proj_w, proj_wb, C_ * C_);
  wconv_kernel<<<dim3(576), dim3(256), 0, stream>>>(fc1_w, fc1_wb, MLP_ * C_);
  wconv_kernel<<<dim3(576), dim3(256), 0, stream>>>(fc2_w, fc2_wb, C_ * MLP_);
  bias_expand_kernel<<<dim3(HEADS_ * NTOK_), dim3(64), 0, stream>>>(rel_bias, biasx);

  // 1. LN1 + shift + window partition -> xw (bf16, window layout)
  ln_kernel<1><<<dim3(T_ / 4), dim3(256), 0, stream>>>(x, g1, b1, xw);

  // 2. QKV GEMM: [T_,384] @ [1152,384]^T -> qkv (bf16)
  mfma_gemm<0><<<dim3(1152 / BN, T_ / BM), dim3(256), 0, stream>>>(
      xw, qkv_wb, qkv_b, (void*)qkvb, nullptr, T_, 1152, 384);

  // 3. MFMA windowed attention -> attn_out
  attn_mfma_kernel<<<dim3((T_ / NTOK_) * HEADS_ / AW), dim3(64 * AW), 0, stream>>>(
      qkvb, biasx, attn_out);

  // 4. proj GEMM + window-reverse + unshift + residual -> d_out = x1 (f32)
  mfma_gemm<2><<<dim3(384 / BN, T_ / BM), dim3(256), 0, stream>>>(
      attn_out, proj_wb, proj_b, (void*)out, x, T_, 384, 384);

  // 5. LN2 on x1 -> h2 (bf16)
  ln_kernel<0><<<dim3(T_ / 4), dim3(256), 0, stream>>>(out, g2, b2, h2);

  // 6. MLP in 2 token-chunks (hid_chunk fits below the weight zone):
  //    FC1: h2[c] @ fc1^T -> gelu -> hidc;  FC2: d_out[c] += hidc @ fc2^T
  for (int chk = 0; chk < 2; ++chk) {
    const size_t row0 = (size_t)chk * TCH_;
    mfma_gemm<1><<<dim3(MLP_ / BN, TCH_ / BM), dim3(256), 0, stream>>>(
        h2 + row0 * C_, fc1_wb, fc1_b, (void*)hidc, nullptr, TCH_, MLP_, 384);
    mfma_gemm<3><<<dim3(384 / BN, TCH_ / BM), dim3(256), 0, stream>>>(
        hidc, fc2_wb, fc2_b, (void*)(out + row0 * C_), nullptr, TCH_, 384, MLP_);
  }
}

// Round 8
// 975.160 us; speedup vs baseline: 1.2599x; 1.1535x over previous
//
#include <hip/hip_runtime.h>
#include <hip/hip_bf16.h>
#include <math.h>

#define B_      32
#define H_      56
#define W_      56
#define C_      384
#define HEADS_  12
#define WIN_    7
#define SHIFT_  3
#define NTOK_   49
#define HD_     32
#define T_      100352   // B_*H_*W_
#define MLP_    1536
#define TCH_    50176    // T_/2, MLP token chunk

typedef __bf16 bf16x8 __attribute__((ext_vector_type(8)));
typedef unsigned short u16x8 __attribute__((ext_vector_type(8)));
typedef float  f32x4  __attribute__((ext_vector_type(4)));

__device__ __forceinline__ float bf2f(unsigned short u) {
  union { unsigned int i; float f; } v; v.i = ((unsigned int)u) << 16; return v.f;
}
__device__ __forceinline__ unsigned short f2bf(float f) {
  union { float f; unsigned int i; } v; v.f = f;
  unsigned int x = v.i;
  return (unsigned short)((x + 0x7fffu + ((x >> 16) & 1u)) >> 16);
}
// fast tanh-GELU (max |err| ~1e-3 pre-FC2; negligible after 0.02-scale weights)
__device__ __forceinline__ float gelu_fast(float x) {
  const float t = 0.79788456f * x * (1.0f + 0.044715f * x * x);
  const float e = __expf(2.0f * t);
  const float th = 1.0f - 2.0f / (e + 1.0f);   // tanh(t), inf-safe
  return 0.5f * x * (1.0f + th);
}
__device__ __forceinline__ void gload_lds16(const void* g, void* l) {
  __builtin_amdgcn_global_load_lds(
      (const __attribute__((address_space(1))) void*)g,
      (__attribute__((address_space(3))) void*)l, 16, 0, 0);
}
__device__ __forceinline__ bf16x8 ldg8(const unsigned short* p) {
  u16x8 v = *(const u16x8*)p;
  return __builtin_bit_cast(bf16x8, v);
}

// ---------------- merged f32 -> bf16 weight converts (1 launch) -------------
// region block counts: qkv 432, proj 144, fc1 576, fc2 576 (1024 elems/block)
__global__ __launch_bounds__(256)
void wconv_all_kernel(const float* __restrict__ s0, unsigned short* __restrict__ d0,
                      const float* __restrict__ s1, unsigned short* __restrict__ d1,
                      const float* __restrict__ s2, unsigned short* __restrict__ d2,
                      const float* __restrict__ s3, unsigned short* __restrict__ d3) {
  int b = blockIdx.x;
  const float* src; unsigned short* dst;
  if (b < 432)       { src = s0; dst = d0; }
  else if (b < 576)  { src = s1; dst = d1; b -= 432; }
  else if (b < 1152) { src = s2; dst = d2; b -= 576; }
  else               { src = s3; dst = d3; b -= 1152; }
  const int i = (b * 256 + threadIdx.x) * 4;
  const float4 v = *(const float4*)(src + i);
  ushort4 o;
  o.x = f2bf(v.x); o.y = f2bf(v.y); o.z = f2bf(v.z); o.w = f2bf(v.w);
  *(ushort4*)(dst + i) = o;
}

// ---------------- LayerNorm: 4 rows / 256-thread block ----------------------
template<int REMAP>
__global__ __launch_bounds__(256)
void ln_kernel(const float* __restrict__ xin, const float* __restrict__ g,
               const float* __restrict__ bb, unsigned short* __restrict__ outbf) {
  const int m = blockIdx.x * 4 + (threadIdx.x >> 6);
  const int lane = threadIdx.x & 63;
  size_t src;
  if (REMAP) {
    int w = m / NTOK_, t = m - w * NTOK_;
    int bz = w >> 6, widx = w & 63;
    int wh = widx >> 3, ww = widx & 7;
    int ih = t / WIN_, iw = t - ih * WIN_;
    int gh = (wh * WIN_ + ih + SHIFT_) % H_;
    int gw = (ww * WIN_ + iw + SHIFT_) % W_;
    src = ((size_t)bz * (H_ * W_) + gh * W_ + gw) * C_;
  } else {
    src = (size_t)m * C_;
  }
  const float* row = xin + src;
  float v[6]; float s = 0.f, s2 = 0.f;
#pragma unroll
  for (int u = 0; u < 6; ++u) {
    v[u] = row[lane + 64 * u];
    s += v[u]; s2 += v[u] * v[u];
  }
#pragma unroll
  for (int off = 32; off; off >>= 1) {
    s  += __shfl_xor(s, off);
    s2 += __shfl_xor(s2, off);
  }
  const float mean = s * (1.0f / C_);
  const float var  = s2 * (1.0f / C_) - mean * mean;
  const float rstd = rsqrtf(var + 1e-5f);
  unsigned short* orow = outbf + (size_t)m * C_;
#pragma unroll
  for (int u = 0; u < 6; ++u) {
    int c = lane + 64 * u;
    orow[c] = f2bf((v[u] - mean) * rstd * g[c] + bb[c]);
  }
}

// ---------------- MFMA GEMM (unchanged from R7: dbuf + vmcnt(8)) ------------
#define BM 128
#define BN 128
#define BKg 64

template<int EPI>
__global__ __launch_bounds__(256)
void mfma_gemm(const unsigned short* __restrict__ A,   // [M,K] bf16
               const unsigned short* __restrict__ Wb,  // [N,K] bf16
               const float* __restrict__ bias,
               void* __restrict__ outv,
               const float* __restrict__ resid,
               int M, int Nn, int K) {
  __shared__ unsigned short Al[2][BM * BKg];
  __shared__ unsigned short Bl[2][BM * BKg];
  const int t    = threadIdx.x;
  const int wid  = t >> 6;
  const int lane = t & 63;
  const int wr   = wid >> 1, wc = wid & 1;

  const unsigned int nb = gridDim.x * gridDim.y;
  unsigned int lin = blockIdx.y * gridDim.x + blockIdx.x;
  lin = (lin & 7) * (nb >> 3) + (lin >> 3);
  const int m0 = (int)(lin / gridDim.x) * BM;
  const int n0 = (int)(lin % gridDim.x) * BN;

  f32x4 acc[4][4] = {};

  const int sr8    = lane >> 3;
  const int schunk = (lane & 7) ^ (sr8 & 7);
  const int fr  = lane & 15;
  const int fq  = lane >> 4;

  const int nk = K / BKg;

#define STAGE_(ks, buf)                                                        \
  {                                                                            \
    const int k0_ = (ks) * BKg;                                                \
    _Pragma("unroll")                                                          \
    for (int i = 0; i < 4; ++i) {                                              \
      const int r = i * 32 + wid * 8 + sr8;                                    \
      gload_lds16(A + (size_t)(m0 + r) * K + k0_ + schunk * 8,                 \
                  (void*)(&Al[buf][(i * 32 + wid * 8) * BKg]));                \
      gload_lds16(Wb + (size_t)(n0 + r) * K + k0_ + schunk * 8,                \
                  (void*)(&Bl[buf][(i * 32 + wid * 8) * BKg]));                \
    }                                                                          \
  }

  STAGE_(0, 0);
  int cur = 0;

  for (int ks = 0; ks < nk; ++ks) {
    if (ks + 1 < nk) {
      STAGE_(ks + 1, cur ^ 1);
      asm volatile("s_waitcnt vmcnt(8)" ::: "memory");
    } else {
      asm volatile("s_waitcnt vmcnt(0)" ::: "memory");
    }
    __builtin_amdgcn_sched_barrier(0);
    __builtin_amdgcn_s_barrier();
    __builtin_amdgcn_sched_barrier(0);

    const unsigned short* Ab = &Al[cur][0];
    const unsigned short* Bb = &Bl[cur][0];
#pragma unroll
    for (int kk = 0; kk < 2; ++kk) {
      bf16x8 af[4], bfr[4];
#pragma unroll
      for (int mi = 0; mi < 4; ++mi) {
        const int row = wr * 64 + mi * 16 + fr;
        const int ch  = (kk * 4 + fq) ^ (row & 7);
        af[mi] = *(const bf16x8*)(Ab + (size_t)row * BKg + ch * 8);
      }
#pragma unroll
      for (int ni = 0; ni < 4; ++ni) {
        const int row = wc * 64 + ni * 16 + fr;
        const int ch  = (kk * 4 + fq) ^ (row & 7);
        bfr[ni] = *(const bf16x8*)(Bb + (size_t)row * BKg + ch * 8);
      }
#pragma unroll
      for (int mi = 0; mi < 4; ++mi)
#pragma unroll
        for (int ni = 0; ni < 4; ++ni)
          acc[mi][ni] = __builtin_amdgcn_mfma_f32_16x16x32_bf16(
              af[mi], bfr[ni], acc[mi][ni], 0, 0, 0);
    }

    __builtin_amdgcn_sched_barrier(0);
    __builtin_amdgcn_s_barrier();
    __builtin_amdgcn_sched_barrier(0);
    cur ^= 1;
  }
#undef STAGE_

  const int ecol  = fr;
  const int erow0 = fq * 4;
#pragma unroll
  for (int mi = 0; mi < 4; ++mi) {
#pragma unroll
    for (int r = 0; r < 4; ++r) {
      const int m = m0 + wr * 64 + mi * 16 + erow0 + r;
      size_t dstbase = 0;
      if (EPI == 2) {
        int w = m / NTOK_, tt = m - w * NTOK_;
        int bz = w >> 6, widx = w & 63;
        int wh = widx >> 3, ww = widx & 7;
        int ih = tt / WIN_, iw = tt - ih * WIN_;
        int gh = (wh * WIN_ + ih + SHIFT_) % H_;
        int gw = (ww * WIN_ + iw + SHIFT_) % W_;
        dstbase = ((size_t)bz * (H_ * W_) + gh * W_ + gw) * C_;
      }
#pragma unroll
      for (int ni = 0; ni < 4; ++ni) {
        const int n = n0 + wc * 64 + ni * 16 + ecol;
        float val = acc[mi][ni][r] + bias[n];
        if (EPI == 0) {
          ((unsigned short*)outv)[(size_t)m * Nn + n] = f2bf(val);
        } else if (EPI == 1) {
          ((unsigned short*)outv)[(size_t)m * Nn + n] = f2bf(gelu_fast(val));
        } else if (EPI == 2) {
          ((float*)outv)[dstbase + n] = resid[dstbase + n] + val;
        } else {
          float* o = (float*)outv + (size_t)m * Nn + n;
          *o += val;
        }
      }
    }
  }
}

// ---------------- bias expansion: rel_bias[169,12] -> biasx[12][49][64] -----
// j-dim padded to 64 (zeros) so attention can float4-load aligned bias rows.
__global__ __launch_bounds__(64)
void bias_expand_kernel(const float* __restrict__ rel_bias,
                        float* __restrict__ biasx) {
  const int hi = blockIdx.x;              // head*49 + i
  const int head = hi / NTOK_, i = hi - head * NTOK_;
  const int j = threadIdx.x;              // 0..63
  float v = 0.f;
  if (j < NTOK_) {
    const int ih = i / 7, iw = i - ih * 7;
    const int jh = j / 7, jw = j - jh * 7;
    const int ridx = (ih - jh + 6) * 13 + (iw - jw + 6);
    v = rel_bias[ridx * HEADS_ + head];
  }
  biasx[(size_t)hi * 64 + j] = v;
}

// ---------------- MFMA windowed attention, SWAPPED QK^T ---------------------
// S^T = mfma(K, Q): lane holds, per query-frag qi, 16 key-values in registers
// (j = nj*16 + fq*4 + r). Row softmax = 15 local fmax + 2 shfl (vs 8 shfl/row).
// P written as packed b64 (4 consecutive j). PV unchanged.
#define AW 2
__global__ __launch_bounds__(64 * AW)
void attn_mfma_kernel(const unsigned short* __restrict__ qkv,  // [T_,1152] bf16
                      const float* __restrict__ biasx,         // [12][49][64]
                      unsigned short* __restrict__ out) {      // [T_,384] bf16
  __shared__ unsigned short sP[AW][64 * 72];   // P (rows=i, cols=j), stride 72
  __shared__ unsigned short sVT[AW][32 * 72];  // V^T (rows=d, cols=j)
  __shared__ float sRI[AW][64];                // per-row 1/sum
  const int wid  = threadIdx.x >> 6;
  const int lane = threadIdx.x & 63;
  const int task = blockIdx.x * AW + wid;
  const int w    = task / HEADS_;
  const int head = task - w * HEADS_;
  const int widx = w & 63;
  const int wh = widx >> 3, ww = widx & 7;
  const bool edge = (wh == 7) || (ww == 7);
  const int c  = lane & 15;
  const int fq = lane >> 4;
  unsigned short* Pl = sP[wid];
  unsigned short* Vl = sVT[wid];
  float* Ri = sRI[wid];
  const unsigned short* qw = qkv + (size_t)w * NTOK_ * (3 * C_);

  // ---- V loads ----
  u16x8 vv[4];
#pragma unroll
  for (int p = 0; p < 4; ++p)
    vv[p] = *(const u16x8*)(qw + (size_t)(p * 16 + c) * (3 * C_) + 2 * C_ + head * HD_ + fq * 8);

  // ---- K as A-frags (row j), Q as B-frags (col i) ----
  bf16x8 kf[4], qf[4];
#pragma unroll
  for (int nj = 0; nj < 4; ++nj)
    kf[nj] = ldg8(qw + (size_t)(nj * 16 + c) * (3 * C_) + C_ + head * HD_ + fq * 8);
#pragma unroll
  for (int qi = 0; qi < 4; ++qi)
    qf[qi] = ldg8(qw + (size_t)(qi * 16 + c) * (3 * C_) + head * HD_ + fq * 8);

  // ---- S^T = K Q^T : element [j=nj*16+fq*4+r][i=qi*16+c] ----
  const f32x4 zero4 = {0.f, 0.f, 0.f, 0.f};
  f32x4 accT[4][4];
#pragma unroll
  for (int nj = 0; nj < 4; ++nj)
#pragma unroll
    for (int qi = 0; qi < 4; ++qi)
      accT[nj][qi] = __builtin_amdgcn_mfma_f32_16x16x32_bf16(kf[nj], qf[qi], zero4, 0, 0, 0);

  // ---- V^T into wave-private LDS ----
#pragma unroll
  for (int p = 0; p < 4; ++p)
#pragma unroll
    for (int u = 0; u < 8; ++u)
      Vl[(fq * 8 + u) * 72 + p * 16 + c] = (unsigned short)vv[p][u];

  // ---- per-j labels (shared across all rows; j depends only on fq) ----
  int lj16[16];
  unsigned jpad = 0;
#pragma unroll
  for (int tt = 0; tt < 16; ++tt) {
    const int j = (tt >> 2) * 16 + fq * 4 + (tt & 3);
    int lj = 0;
    if (j >= NTOK_) jpad |= (1u << tt);
    else if (edge) {
      const int jh = j / 7, jw2 = j - jh * 7;
      const int shj = wh * 7 + jh, swj = ww * 7 + jw2;
      lj = (shj < 49 ? 0 : (shj < 53 ? 1 : 2)) * 3 + (swj < 49 ? 0 : (swj < 53 ? 1 : 2));
    }
    lj16[tt] = lj;
  }

  // ---- softmax: row i = qi*16+c, values mostly in-lane ----
  const float* bh = biasx + (size_t)head * (NTOK_ * 64);
#pragma unroll
  for (int qi = 0; qi < 4; ++qi) {
    const int i  = qi * 16 + c;
    const int ic = i < NTOK_ ? i : 0;
    int li = 0;
    if (edge) {
      const int ih = ic / 7, iw2 = ic - ih * 7;
      const int shi = wh * 7 + ih, swi = ww * 7 + iw2;
      li = (shi < 49 ? 0 : (shi < 53 ? 1 : 2)) * 3 + (swi < 49 ? 0 : (swi < 53 ? 1 : 2));
    }
    float sv[16];
#pragma unroll
    for (int nj = 0; nj < 4; ++nj) {
      const float4 b4 = *(const float4*)(bh + ic * 64 + nj * 16 + fq * 4);
      const float* b4p = (const float*)&b4;
#pragma unroll
      for (int r = 0; r < 4; ++r) {
        const int tt = nj * 4 + r;
        float s = accT[nj][qi][r] * 0.17677669529663687f + b4p[r];
        if (edge && lj16[tt] != li) s -= 100.f;
        if (jpad & (1u << tt)) s = -1e30f;
        sv[tt] = s;
      }
    }
    float mx = sv[0];
#pragma unroll
    for (int tt = 1; tt < 16; ++tt) mx = fmaxf(mx, sv[tt]);
    mx = fmaxf(mx, __shfl_xor(mx, 16));
    mx = fmaxf(mx, __shfl_xor(mx, 32));
    float e[16]; float sm = 0.f;
#pragma unroll
    for (int tt = 0; tt < 16; ++tt) { e[tt] = __expf(sv[tt] - mx); sm += e[tt]; }
    sm += __shfl_xor(sm, 16);
    sm += __shfl_xor(sm, 32);
    if (fq == 0) Ri[i] = 1.0f / sm;
#pragma unroll
    for (int nj = 0; nj < 4; ++nj) {
      ushort4 pk;
      pk.x = f2bf(e[nj * 4 + 0]); pk.y = f2bf(e[nj * 4 + 1]);
      pk.z = f2bf(e[nj * 4 + 2]); pk.w = f2bf(e[nj * 4 + 3]);
      *(ushort4*)(Pl + (size_t)i * 72 + nj * 16 + fq * 4) = pk;
    }
  }

  // ---- O = P V (A = P rows from LDS, B = V^T rows from LDS) ----
  f32x4 accO[4][2] = {};
#pragma unroll
  for (int kk = 0; kk < 2; ++kk) {
    bf16x8 ap[4], bv[2];
#pragma unroll
    for (int mi = 0; mi < 4; ++mi)
      ap[mi] = __builtin_bit_cast(bf16x8,
          *(const u16x8*)(Pl + (mi * 16 + c) * 72 + kk * 32 + fq * 8));
#pragma unroll
    for (int nd = 0; nd < 2; ++nd)
      bv[nd] = __builtin_bit_cast(bf16x8,
          *(const u16x8*)(Vl + (nd * 16 + c) * 72 + kk * 32 + fq * 8));
#pragma unroll
    for (int mi = 0; mi < 4; ++mi)
#pragma unroll
      for (int nd = 0; nd < 2; ++nd)
        accO[mi][nd] = __builtin_amdgcn_mfma_f32_16x16x32_bf16(ap[mi], bv[nd], accO[mi][nd], 0, 0, 0);
  }

  // ---- store rows < 49, scaled by 1/rowsum (from LDS) ----
#pragma unroll
  for (int mi = 0; mi < 4; ++mi)
#pragma unroll
    for (int r = 0; r < 4; ++r) {
      const int i = mi * 16 + fq * 4 + r;
      if (i < NTOK_) {
        const float inv = Ri[i];
#pragma unroll
        for (int nd = 0; nd < 2; ++nd)
          out[(size_t)(w * NTOK_ + i) * C_ + head * HD_ + nd * 16 + c] =
              f2bf(accO[mi][nd][r] * inv);
      }
    }
}

// -----------------------------------------------------------------------------
extern "C" void kernel_launch(void* const* d_in, const int* in_sizes, int n_in,
                              void* d_out, int out_size, void* d_ws, size_t ws_size,
                              hipStream_t stream) {
  const float* x        = (const float*)d_in[0];
  const float* g1       = (const float*)d_in[1];
  const float* b1       = (const float*)d_in[2];
  const float* qkv_w    = (const float*)d_in[3];
  const float* qkv_b    = (const float*)d_in[4];
  const float* rel_bias = (const float*)d_in[5];
  const float* proj_w   = (const float*)d_in[6];
  const float* proj_b   = (const float*)d_in[7];
  const float* g2       = (const float*)d_in[8];
  const float* b2       = (const float*)d_in[9];
  const float* fc1_w    = (const float*)d_in[10];
  const float* fc1_b    = (const float*)d_in[11];
  const float* fc2_w    = (const float*)d_in[12];
  const float* fc2_b    = (const float*)d_in[13];
  float* out = (float*)d_out;

  char* ws = (char*)d_ws;
  // region A [0, 77,070,336): xw -> attn_out -> h2
  // region B [77,070,336, 308,281,344): qkvb (231 MB); post-attn reused as
  //   hid_chunk (154,140,672 B). weights zone (static): see offsets below.
  unsigned short* xw   = (unsigned short*)(ws);
  unsigned short* qkvb = (unsigned short*)(ws + 77070336);
  unsigned short* attn_out = xw;
  unsigned short* h2   = xw;
  unsigned short* hidc = qkvb;
  unsigned short* qkv_wb  = (unsigned short*)(ws + 308412416); // 884,736 B
  unsigned short* proj_wb = (unsigned short*)(ws + 309297152); // 294,912 B
  unsigned short* fc1_wb  = (unsigned short*)(ws + 309592064); // 1,179,648 B
  unsigned short* fc2_wb  = (unsigned short*)(ws + 310771712); // 1,179,648 B
  float*          biasx   = (float*)(ws + 311951360);          // 150,528 B

  // 0. weight converts (1 launch) + padded bias expansion
  wconv_all_kernel<<<dim3(1728), dim3(256), 0, stream>>>(
      qkv_w, qkv_wb, proj_w, proj_wb, fc1_w, fc1_wb, fc2_w, fc2_wb);
  bias_expand_kernel<<<dim3(HEADS_ * NTOK_), dim3(64), 0, stream>>>(rel_bias, biasx);

  // 1. LN1 + shift + window partition -> xw (bf16, window layout)
  ln_kernel<1><<<dim3(T_ / 4), dim3(256), 0, stream>>>(x, g1, b1, xw);

  // 2. QKV GEMM: [T_,384] @ [1152,384]^T -> qkv (bf16)
  mfma_gemm<0><<<dim3(1152 / BN, T_ / BM), dim3(256), 0, stream>>>(
      xw, qkv_wb, qkv_b, (void*)qkvb, nullptr, T_, 1152, 384);

  // 3. MFMA windowed attention (swapped QK^T) -> attn_out
  attn_mfma_kernel<<<dim3((T_ / NTOK_) * HEADS_ / AW), dim3(64 * AW), 0, stream>>>(
      qkvb, biasx, attn_out);

  // 4. proj GEMM + window-reverse + unshift + residual -> d_out = x1 (f32)
  mfma_gemm<2><<<dim3(384 / BN, T_ / BM), dim3(256), 0, stream>>>(
      attn_out, proj_wb, proj_b, (void*)out, x, T_, 384, 384);

  // 5. LN2 on x1 -> h2 (bf16)
  ln_kernel<0><<<dim3(T_ / 4), dim3(256), 0, stream>>>(out, g2, b2, h2);

  // 6. MLP in 2 token-chunks (hid_chunk stays below the weight zone)
  for (int chk = 0; chk < 2; ++chk) {
    const size_t row0 = (size_t)chk * TCH_;
    mfma_gemm<1><<<dim3(MLP_ / BN, TCH_ / BM), dim3(256), 0, stream>>>(
        h2 + row0 * C_, fc1_wb, fc1_b, (void*)hidc, nullptr, TCH_, MLP_, 384);
    mfma_gemm<3><<<dim3(384 / BN, TCH_ / BM), dim3(256), 0, stream>>>(
        hidc, fc2_wb, fc2_b, (void*)(out + row0 * C_), nullptr, TCH_, 384, MLP_);
  }
}

// Round 9
// 876.141 us; speedup vs baseline: 1.4023x; 1.1130x over previous
//
#include <hip/hip_runtime.h>
#include <hip/hip_bf16.h>
#include <math.h>

#define B_      32
#define H_      56
#define W_      56
#define C_      384
#define HEADS_  12
#define WIN_    7
#define SHIFT_  3
#define NTOK_   49
#define HD_     32
#define T_      100352   // B_*H_*W_
#define MLP_    1536
#define TCH_    50176    // T_/2, MLP token chunk

typedef __bf16 bf16x8 __attribute__((ext_vector_type(8)));
typedef unsigned short u16x8 __attribute__((ext_vector_type(8)));
typedef float  f32x4  __attribute__((ext_vector_type(4)));

__device__ __forceinline__ float bf2f(unsigned short u) {
  union { unsigned int i; float f; } v; v.i = ((unsigned int)u) << 16; return v.f;
}
__device__ __forceinline__ unsigned short f2bf(float f) {
  union { float f; unsigned int i; } v; v.f = f;
  unsigned int x = v.i;
  return (unsigned short)((x + 0x7fffu + ((x >> 16) & 1u)) >> 16);
}
// fast tanh-GELU (max |err| ~1e-3 pre-FC2; negligible after 0.02-scale weights)
__device__ __forceinline__ float gelu_fast(float x) {
  const float t = 0.79788456f * x * (1.0f + 0.044715f * x * x);
  const float e = __expf(2.0f * t);
  const float th = 1.0f - 2.0f / (e + 1.0f);   // tanh(t), inf-safe
  return 0.5f * x * (1.0f + th);
}
__device__ __forceinline__ void gload_lds16(const void* g, void* l) {
  __builtin_amdgcn_global_load_lds(
      (const __attribute__((address_space(1))) void*)g,
      (__attribute__((address_space(3))) void*)l, 16, 0, 0);
}
__device__ __forceinline__ bf16x8 ldg8(const unsigned short* p) {
  u16x8 v = *(const u16x8*)p;
  return __builtin_bit_cast(bf16x8, v);
}

// ---------------- merged f32 -> bf16 weight converts (1 launch) -------------
__global__ __launch_bounds__(256)
void wconv_all_kernel(const float* __restrict__ s0, unsigned short* __restrict__ d0,
                      const float* __restrict__ s1, unsigned short* __restrict__ d1,
                      const float* __restrict__ s2, unsigned short* __restrict__ d2,
                      const float* __restrict__ s3, unsigned short* __restrict__ d3) {
  int b = blockIdx.x;
  const float* src; unsigned short* dst;
  if (b < 432)       { src = s0; dst = d0; }
  else if (b < 576)  { src = s1; dst = d1; b -= 432; }
  else if (b < 1152) { src = s2; dst = d2; b -= 576; }
  else               { src = s3; dst = d3; b -= 1152; }
  const int i = (b * 256 + threadIdx.x) * 4;
  const float4 v = *(const float4*)(src + i);
  ushort4 o;
  o.x = f2bf(v.x); o.y = f2bf(v.y); o.z = f2bf(v.z); o.w = f2bf(v.w);
  *(ushort4*)(dst + i) = o;
}

// ---------------- LayerNorm: 4 rows / 256-thread block ----------------------
template<int REMAP>
__global__ __launch_bounds__(256)
void ln_kernel(const float* __restrict__ xin, const float* __restrict__ g,
               const float* __restrict__ bb, unsigned short* __restrict__ outbf) {
  const int m = blockIdx.x * 4 + (threadIdx.x >> 6);
  const int lane = threadIdx.x & 63;
  size_t src;
  if (REMAP) {
    int w = m / NTOK_, t = m - w * NTOK_;
    int bz = w >> 6, widx = w & 63;
    int wh = widx >> 3, ww = widx & 7;
    int ih = t / WIN_, iw = t - ih * WIN_;
    int gh = (wh * WIN_ + ih + SHIFT_) % H_;
    int gw = (ww * WIN_ + iw + SHIFT_) % W_;
    src = ((size_t)bz * (H_ * W_) + gh * W_ + gw) * C_;
  } else {
    src = (size_t)m * C_;
  }
  const float* row = xin + src;
  float v[6]; float s = 0.f, s2 = 0.f;
#pragma unroll
  for (int u = 0; u < 6; ++u) {
    v[u] = row[lane + 64 * u];
    s += v[u]; s2 += v[u] * v[u];
  }
#pragma unroll
  for (int off = 32; off; off >>= 1) {
    s  += __shfl_xor(s, off);
    s2 += __shfl_xor(s2, off);
  }
  const float mean = s * (1.0f / C_);
  const float var  = s2 * (1.0f / C_) - mean * mean;
  const float rstd = rsqrtf(var + 1e-5f);
  unsigned short* orow = outbf + (size_t)m * C_;
#pragma unroll
  for (int u = 0; u < 6; ++u) {
    int c = lane + 64 * u;
    orow[c] = f2bf((v[u] - mean) * rstd * g[c] + bb[c]);
  }
}

// ---------------- MFMA GEMM: 256x128 tile, 8 waves, single-buffer 48KB ------
// 2 blocks/CU (VGPR-capped 16 waves/CU). Bijective XCD-chunked block swizzle
// (m204: works for any grid size). A,B staged via global_load_lds w/
// pre-swizzled source. EPI: 0 bf16; 1 gelu->bf16; 2 win-reverse+resid->f32;
// 3 f32 +=
#define BM 256
#define BN 128
#define BKg 64

template<int EPI>
__global__ __launch_bounds__(512)
void mfma_gemm(const unsigned short* __restrict__ A,   // [M,K] bf16
               const unsigned short* __restrict__ Wb,  // [N,K] bf16
               const float* __restrict__ bias,
               void* __restrict__ outv,
               const float* __restrict__ resid,
               int M, int Nn, int K) {
  __shared__ unsigned short Al[BM * BKg];   // 32 KB
  __shared__ unsigned short Bl[BN * BKg];   // 16 KB
  const int t    = threadIdx.x;
  const int wid  = t >> 6;                  // 0..7
  const int lane = t & 63;
  const int wr   = wid >> 1, wc = wid & 1;  // 4 x 2 wave grid

  // bijective XCD-chunked swizzle (any nb)
  const unsigned int nb = gridDim.x * gridDim.y;
  const unsigned int lin = blockIdx.y * gridDim.x + blockIdx.x;
  const unsigned int q = nb >> 3, r = nb & 7;
  const unsigned int xcd = lin & 7, idx = lin >> 3;
  const unsigned int wg = (xcd < r ? xcd * (q + 1) : r * (q + 1) + (xcd - r) * q) + idx;
  const int m0 = (int)(wg / gridDim.x) * BM;
  const int n0 = (int)(wg % gridDim.x) * BN;

  f32x4 acc[4][4] = {};

  const int sr8    = lane >> 3;
  const int schunk = (lane & 7) ^ (sr8 & 7);
  const int fr  = lane & 15;
  const int fq  = lane >> 4;

  for (int k0 = 0; k0 < K; k0 += BKg) {
    __syncthreads();
    // A: 4 issues x 8 rows/wave (256 rows); B: 2 issues (128 rows)
#pragma unroll
    for (int i = 0; i < 4; ++i) {
      const int rr = i * 64 + wid * 8 + sr8;
      gload_lds16(A + (size_t)(m0 + rr) * K + k0 + schunk * 8,
                  (void*)(Al + (size_t)(i * 64 + wid * 8) * BKg));
    }
#pragma unroll
    for (int i = 0; i < 2; ++i) {
      const int rr = i * 64 + wid * 8 + sr8;
      gload_lds16(Wb + (size_t)(n0 + rr) * K + k0 + schunk * 8,
                  (void*)(Bl + (size_t)(i * 64 + wid * 8) * BKg));
    }
    __syncthreads();

#pragma unroll
    for (int kk = 0; kk < 2; ++kk) {
      bf16x8 af[4], bfr[4];
#pragma unroll
      for (int mi = 0; mi < 4; ++mi) {
        const int row = wr * 64 + mi * 16 + fr;
        const int ch  = (kk * 4 + fq) ^ (row & 7);
        af[mi] = *(const bf16x8*)(Al + (size_t)row * BKg + ch * 8);
      }
#pragma unroll
      for (int ni = 0; ni < 4; ++ni) {
        const int row = wc * 64 + ni * 16 + fr;
        const int ch  = (kk * 4 + fq) ^ (row & 7);
        bfr[ni] = *(const bf16x8*)(Bl + (size_t)row * BKg + ch * 8);
      }
#pragma unroll
      for (int mi = 0; mi < 4; ++mi)
#pragma unroll
        for (int ni = 0; ni < 4; ++ni)
          acc[mi][ni] = __builtin_amdgcn_mfma_f32_16x16x32_bf16(
              af[mi], bfr[ni], acc[mi][ni], 0, 0, 0);
    }
  }

  const int ecol  = fr;
  const int erow0 = fq * 4;
#pragma unroll
  for (int mi = 0; mi < 4; ++mi) {
#pragma unroll
    for (int r2 = 0; r2 < 4; ++r2) {
      const int m = m0 + wr * 64 + mi * 16 + erow0 + r2;
      size_t dstbase = 0;
      if (EPI == 2) {
        int w = m / NTOK_, tt = m - w * NTOK_;
        int bz = w >> 6, widx = w & 63;
        int wh = widx >> 3, ww = widx & 7;
        int ih = tt / WIN_, iw = tt - ih * WIN_;
        int gh = (wh * WIN_ + ih + SHIFT_) % H_;
        int gw = (ww * WIN_ + iw + SHIFT_) % W_;
        dstbase = ((size_t)bz * (H_ * W_) + gh * W_ + gw) * C_;
      }
#pragma unroll
      for (int ni = 0; ni < 4; ++ni) {
        const int n = n0 + wc * 64 + ni * 16 + ecol;
        float val = acc[mi][ni][r2] + bias[n];
        if (EPI == 0) {
          ((unsigned short*)outv)[(size_t)m * Nn + n] = f2bf(val);
        } else if (EPI == 1) {
          ((unsigned short*)outv)[(size_t)m * Nn + n] = f2bf(gelu_fast(val));
        } else if (EPI == 2) {
          ((float*)outv)[dstbase + n] = resid[dstbase + n] + val;
        } else {
          float* o = (float*)outv + (size_t)m * Nn + n;
          *o += val;
        }
      }
    }
  }
}

// ---------------- bias expansion: rel_bias[169,12] -> biasx[12][49][64] -----
__global__ __launch_bounds__(64)
void bias_expand_kernel(const float* __restrict__ rel_bias,
                        float* __restrict__ biasx) {
  const int hi = blockIdx.x;              // head*49 + i
  const int head = hi / NTOK_, i = hi - head * NTOK_;
  const int j = threadIdx.x;              // 0..63
  float v = 0.f;
  if (j < NTOK_) {
    const int ih = i / 7, iw = i - ih * 7;
    const int jh = j / 7, jw = j - jh * 7;
    const int ridx = (ih - jh + 6) * 13 + (iw - jw + 6);
    v = rel_bias[ridx * HEADS_ + head];
  }
  biasx[(size_t)hi * 64 + j] = v;
}

// ---------------- MFMA windowed attention, SWAPPED QK^T (unchanged R8) ------
#define AW 2
__global__ __launch_bounds__(64 * AW)
void attn_mfma_kernel(const unsigned short* __restrict__ qkv,  // [T_,1152] bf16
                      const float* __restrict__ biasx,         // [12][49][64]
                      unsigned short* __restrict__ out) {      // [T_,384] bf16
  __shared__ unsigned short sP[AW][64 * 72];
  __shared__ unsigned short sVT[AW][32 * 72];
  __shared__ float sRI[AW][64];
  const int wid  = threadIdx.x >> 6;
  const int lane = threadIdx.x & 63;
  const int task = blockIdx.x * AW + wid;
  const int w    = task / HEADS_;
  const int head = task - w * HEADS_;
  const int widx = w & 63;
  const int wh = widx >> 3, ww = widx & 7;
  const bool edge = (wh == 7) || (ww == 7);
  const int c  = lane & 15;
  const int fq = lane >> 4;
  unsigned short* Pl = sP[wid];
  unsigned short* Vl = sVT[wid];
  float* Ri = sRI[wid];
  const unsigned short* qw = qkv + (size_t)w * NTOK_ * (3 * C_);

  u16x8 vv[4];
#pragma unroll
  for (int p = 0; p < 4; ++p)
    vv[p] = *(const u16x8*)(qw + (size_t)(p * 16 + c) * (3 * C_) + 2 * C_ + head * HD_ + fq * 8);

  bf16x8 kf[4], qf[4];
#pragma unroll
  for (int nj = 0; nj < 4; ++nj)
    kf[nj] = ldg8(qw + (size_t)(nj * 16 + c) * (3 * C_) + C_ + head * HD_ + fq * 8);
#pragma unroll
  for (int qi = 0; qi < 4; ++qi)
    qf[qi] = ldg8(qw + (size_t)(qi * 16 + c) * (3 * C_) + head * HD_ + fq * 8);

  const f32x4 zero4 = {0.f, 0.f, 0.f, 0.f};
  f32x4 accT[4][4];
#pragma unroll
  for (int nj = 0; nj < 4; ++nj)
#pragma unroll
    for (int qi = 0; qi < 4; ++qi)
      accT[nj][qi] = __builtin_amdgcn_mfma_f32_16x16x32_bf16(kf[nj], qf[qi], zero4, 0, 0, 0);

#pragma unroll
  for (int p = 0; p < 4; ++p)
#pragma unroll
    for (int u = 0; u < 8; ++u)
      Vl[(fq * 8 + u) * 72 + p * 16 + c] = (unsigned short)vv[p][u];

  int lj16[16];
  unsigned jpad = 0;
#pragma unroll
  for (int tt = 0; tt < 16; ++tt) {
    const int j = (tt >> 2) * 16 + fq * 4 + (tt & 3);
    int lj = 0;
    if (j >= NTOK_) jpad |= (1u << tt);
    else if (edge) {
      const int jh = j / 7, jw2 = j - jh * 7;
      const int shj = wh * 7 + jh, swj = ww * 7 + jw2;
      lj = (shj < 49 ? 0 : (shj < 53 ? 1 : 2)) * 3 + (swj < 49 ? 0 : (swj < 53 ? 1 : 2));
    }
    lj16[tt] = lj;
  }

  const float* bh = biasx + (size_t)head * (NTOK_ * 64);
#pragma unroll
  for (int qi = 0; qi < 4; ++qi) {
    const int i  = qi * 16 + c;
    const int ic = i < NTOK_ ? i : 0;
    int li = 0;
    if (edge) {
      const int ih = ic / 7, iw2 = ic - ih * 7;
      const int shi = wh * 7 + ih, swi = ww * 7 + iw2;
      li = (shi < 49 ? 0 : (shi < 53 ? 1 : 2)) * 3 + (swi < 49 ? 0 : (swi < 53 ? 1 : 2));
    }
    float sv[16];
#pragma unroll
    for (int nj = 0; nj < 4; ++nj) {
      const float4 b4 = *(const float4*)(bh + ic * 64 + nj * 16 + fq * 4);
      const float* b4p = (const float*)&b4;
#pragma unroll
      for (int r = 0; r < 4; ++r) {
        const int tt = nj * 4 + r;
        float s = accT[nj][qi][r] * 0.17677669529663687f + b4p[r];
        if (edge && lj16[tt] != li) s -= 100.f;
        if (jpad & (1u << tt)) s = -1e30f;
        sv[tt] = s;
      }
    }
    float mx = sv[0];
#pragma unroll
    for (int tt = 1; tt < 16; ++tt) mx = fmaxf(mx, sv[tt]);
    mx = fmaxf(mx, __shfl_xor(mx, 16));
    mx = fmaxf(mx, __shfl_xor(mx, 32));
    float e[16]; float sm = 0.f;
#pragma unroll
    for (int tt = 0; tt < 16; ++tt) { e[tt] = __expf(sv[tt] - mx); sm += e[tt]; }
    sm += __shfl_xor(sm, 16);
    sm += __shfl_xor(sm, 32);
    if (fq == 0) Ri[i] = 1.0f / sm;
#pragma unroll
    for (int nj = 0; nj < 4; ++nj) {
      ushort4 pk;
      pk.x = f2bf(e[nj * 4 + 0]); pk.y = f2bf(e[nj * 4 + 1]);
      pk.z = f2bf(e[nj * 4 + 2]); pk.w = f2bf(e[nj * 4 + 3]);
      *(ushort4*)(Pl + (size_t)i * 72 + nj * 16 + fq * 4) = pk;
    }
  }

  f32x4 accO[4][2] = {};
#pragma unroll
  for (int kk = 0; kk < 2; ++kk) {
    bf16x8 ap[4], bv[2];
#pragma unroll
    for (int mi = 0; mi < 4; ++mi)
      ap[mi] = __builtin_bit_cast(bf16x8,
          *(const u16x8*)(Pl + (mi * 16 + c) * 72 + kk * 32 + fq * 8));
#pragma unroll
    for (int nd = 0; nd < 2; ++nd)
      bv[nd] = __builtin_bit_cast(bf16x8,
          *(const u16x8*)(Vl + (nd * 16 + c) * 72 + kk * 32 + fq * 8));
#pragma unroll
    for (int mi = 0; mi < 4; ++mi)
#pragma unroll
      for (int nd = 0; nd < 2; ++nd)
        accO[mi][nd] = __builtin_amdgcn_mfma_f32_16x16x32_bf16(ap[mi], bv[nd], accO[mi][nd], 0, 0, 0);
  }

#pragma unroll
  for (int mi = 0; mi < 4; ++mi)
#pragma unroll
    for (int r = 0; r < 4; ++r) {
      const int i = mi * 16 + fq * 4 + r;
      if (i < NTOK_) {
        const float inv = Ri[i];
#pragma unroll
        for (int nd = 0; nd < 2; ++nd)
          out[(size_t)(w * NTOK_ + i) * C_ + head * HD_ + nd * 16 + c] =
              f2bf(accO[mi][nd][r] * inv);
      }
    }
}

// -----------------------------------------------------------------------------
extern "C" void kernel_launch(void* const* d_in, const int* in_sizes, int n_in,
                              void* d_out, int out_size, void* d_ws, size_t ws_size,
                              hipStream_t stream) {
  const float* x        = (const float*)d_in[0];
  const float* g1       = (const float*)d_in[1];
  const float* b1       = (const float*)d_in[2];
  const float* qkv_w    = (const float*)d_in[3];
  const float* qkv_b    = (const float*)d_in[4];
  const float* rel_bias = (const float*)d_in[5];
  const float* proj_w   = (const float*)d_in[6];
  const float* proj_b   = (const float*)d_in[7];
  const float* g2       = (const float*)d_in[8];
  const float* b2       = (const float*)d_in[9];
  const float* fc1_w    = (const float*)d_in[10];
  const float* fc1_b    = (const float*)d_in[11];
  const float* fc2_w    = (const float*)d_in[12];
  const float* fc2_b    = (const float*)d_in[13];
  float* out = (float*)d_out;

  char* ws = (char*)d_ws;
  // region A [0, 77,070,336): xw -> attn_out -> h2
  // region B [77,070,336, 308,281,344): qkvb (231 MB); post-attn reused as
  //   hid_chunk (154,140,672 B). weights zone (static): offsets below.
  unsigned short* xw   = (unsigned short*)(ws);
  unsigned short* qkvb = (unsigned short*)(ws + 77070336);
  unsigned short* attn_out = xw;
  unsigned short* h2   = xw;
  unsigned short* hidc = qkvb;
  unsigned short* qkv_wb  = (unsigned short*)(ws + 308412416); // 884,736 B
  unsigned short* proj_wb = (unsigned short*)(ws + 309297152); // 294,912 B
  unsigned short* fc1_wb  = (unsigned short*)(ws + 309592064); // 1,179,648 B
  unsigned short* fc2_wb  = (unsigned short*)(ws + 310771712); // 1,179,648 B
  float*          biasx   = (float*)(ws + 311951360);          // 150,528 B

  // 0. weight converts (1 launch) + padded bias expansion
  wconv_all_kernel<<<dim3(1728), dim3(256), 0, stream>>>(
      qkv_w, qkv_wb, proj_w, proj_wb, fc1_w, fc1_wb, fc2_w, fc2_wb);
  bias_expand_kernel<<<dim3(HEADS_ * NTOK_), dim3(64), 0, stream>>>(rel_bias, biasx);

  // 1. LN1 + shift + window partition -> xw (bf16, window layout)
  ln_kernel<1><<<dim3(T_ / 4), dim3(256), 0, stream>>>(x, g1, b1, xw);

  // 2. QKV GEMM: [T_,384] @ [1152,384]^T -> qkv (bf16)
  mfma_gemm<0><<<dim3(1152 / BN, T_ / BM), dim3(512), 0, stream>>>(
      xw, qkv_wb, qkv_b, (void*)qkvb, nullptr, T_, 1152, 384);

  // 3. MFMA windowed attention (swapped QK^T) -> attn_out
  attn_mfma_kernel<<<dim3((T_ / NTOK_) * HEADS_ / AW), dim3(64 * AW), 0, stream>>>(
      qkvb, biasx, attn_out);

  // 4. proj GEMM + window-reverse + unshift + residual -> d_out = x1 (f32)
  mfma_gemm<2><<<dim3(384 / BN, T_ / BM), dim3(512), 0, stream>>>(
      attn_out, proj_wb, proj_b, (void*)out, x, T_, 384, 384);

  // 5. LN2 on x1 -> h2 (bf16)
  ln_kernel<0><<<dim3(T_ / 4), dim3(256), 0, stream>>>(out, g2, b2, h2);

  // 6. MLP in 2 token-chunks (hid_chunk stays below the weight zone)
  for (int chk = 0; chk < 2; ++chk) {
    const size_t row0 = (size_t)chk * TCH_;
    mfma_gemm<1><<<dim3(MLP_ / BN, TCH_ / BM), dim3(512), 0, stream>>>(
        h2 + row0 * C_, fc1_wb, fc1_b, (void*)hidc, nullptr, TCH_, MLP_, 384);
    mfma_gemm<3><<<dim3(384 / BN, TCH_ / BM), dim3(512), 0, stream>>>(
        hidc, fc2_wb, fc2_b, (void*)(out + row0 * C_), nullptr, TCH_, 384, MLP_);
  }
}